// Round 6
// baseline (305.335 us; speedup 1.0000x reference)
//
#include <hip/hip_runtime.h>

#define M_NODES 50000
#define E_EDGES 600000
#define SCAN_B ((M_NODES + 255) / 256)
#define NCPY 16

typedef short bf16x8 __attribute__((ext_vector_type(8)));
typedef float f32x4 __attribute__((ext_vector_type(4)));

__device__ __forceinline__ unsigned short f2bf(float f){
  unsigned u = __float_as_uint(f);
  u += 0x7FFFu + ((u >> 16) & 1u);
  return (unsigned short)(u >> 16);
}
__device__ __forceinline__ float bf2f(unsigned short h){
  return __uint_as_float(((unsigned)h) << 16);
}
__device__ __forceinline__ unsigned short lob(float x){
  unsigned short h = f2bf(x);
  return f2bf(x - bf2f(h));
}
__device__ __forceinline__ void gl_lds16(const void* g, void* l){
  __builtin_amdgcn_global_load_lds(
      (const __attribute__((address_space(1))) unsigned int*)g,
      (__attribute__((address_space(3))) unsigned int*)l, 16, 0, 0);
}

// ---------- split fp32 h -> split rows [hi128|lo128] ----------
__global__ __launch_bounds__(256) void k_split(const float* __restrict__ H,
    char* __restrict__ X){
  int i = blockIdx.x*256 + threadIdx.x;          // over M*16 granules
  if (i >= M_NODES*16) return;
  int n = i >> 4, j = i & 15;
  const float4 f0 = *reinterpret_cast<const float4*>(H + (size_t)n*128 + j*8);
  const float4 f1 = *reinterpret_cast<const float4*>(H + (size_t)n*128 + j*8 + 4);
  uint4 hq, lq;
  hq.x = (unsigned)f2bf(f0.x) | ((unsigned)f2bf(f0.y) << 16);
  hq.y = (unsigned)f2bf(f0.z) | ((unsigned)f2bf(f0.w) << 16);
  hq.z = (unsigned)f2bf(f1.x) | ((unsigned)f2bf(f1.y) << 16);
  hq.w = (unsigned)f2bf(f1.z) | ((unsigned)f2bf(f1.w) << 16);
  lq.x = (unsigned)lob(f0.x) | ((unsigned)lob(f0.y) << 16);
  lq.y = (unsigned)lob(f0.z) | ((unsigned)lob(f0.w) << 16);
  lq.z = (unsigned)lob(f1.x) | ((unsigned)lob(f1.y) << 16);
  lq.w = (unsigned)lob(f1.z) | ((unsigned)lob(f1.w) << 16);
  *reinterpret_cast<uint4*>(X + (size_t)n*512 + j*16)       = hq;
  *reinterpret_cast<uint4*>(X + (size_t)n*512 + 256 + j*16) = lq;
}

// ---------- all weight preps in one kernel ----------
__global__ __launch_bounds__(256) void k_prep_all(
    const float* __restrict__ ws0, const float* __restrict__ wn0,
    const float* __restrict__ ws1, const float* __restrict__ wn1,
    const float* __restrict__ ws2, const float* __restrict__ wn2,
    const float* __restrict__ lw0, const float* __restrict__ lw1,
    const float* __restrict__ lw2,
    unsigned short* __restrict__ W0h, unsigned short* __restrict__ W0l,
    unsigned short* __restrict__ W1h, unsigned short* __restrict__ W1l,
    unsigned short* __restrict__ W2h, unsigned short* __restrict__ W2l,
    unsigned short* __restrict__ L0h, unsigned short* __restrict__ L0l,
    unsigned short* __restrict__ L1h, unsigned short* __restrict__ L1l,
    unsigned short* __restrict__ L2h, unsigned short* __restrict__ L2l){
  const int b = blockIdx.x, t = threadIdx.x;
  if (b < 384){                      // stacked [ws;wn] -> [N=128][K=256]
    const int wsel = b >> 7;
    const int i = (b & 127)*256 + t;
    const float* Wa = wsel==0?ws0:(wsel==1?ws1:ws2);
    const float* Wb = wsel==0?wn0:(wsel==1?wn1:wn2);
    unsigned short* Th = wsel==0?W0h:(wsel==1?W1h:W2h);
    unsigned short* Tl = wsel==0?W0l:(wsel==1?W1l:W2l);
    int n = i >> 8, k = i & 255;
    float v = (k < 128) ? Wa[k*128 + n] : Wb[(k-128)*128 + n];
    unsigned short hi = f2bf(v);
    Th[n*256 + k] = hi; Tl[n*256 + k] = f2bf(v - bf2f(hi));
  } else if (b < 512){               // lw0/lw1 [128][128] -> [128][128]^T
    const int lsel = (b - 384) >> 6;
    const int i = ((b - 384) & 63)*256 + t;
    const float* W = lsel==0?lw0:lw1;
    unsigned short* Th = lsel==0?L0h:L1h;
    unsigned short* Tl = lsel==0?L0l:L1l;
    int n = i >> 7, k = i & 127;
    float v = W[k*128 + n];
    unsigned short hi = f2bf(v);
    Th[n*128 + k] = hi; Tl[n*128 + k] = f2bf(v - bf2f(hi));
  } else {                           // lw2 [128][64] -> [64][128]^T
    const int i = (b - 512)*256 + t;
    if (i >= 64*128) return;
    int n = i >> 7, k = i & 127;
    float v = lw2[k*64 + n];
    unsigned short hi = f2bf(v);
    L2h[n*128 + k] = hi; L2l[n*128 + k] = f2bf(v - bf2f(hi));
  }
}

// ---------- degree histogram (16-way replicated) + graph-id histogram ----------
__global__ __launch_bounds__(256) void k_hist(const int* __restrict__ dst, int* __restrict__ cnt16,
    const int* __restrict__ gid, int* __restrict__ gcnt){
  const int c = blockIdx.x & (NCPY-1);
  int i = blockIdx.x*256 + threadIdx.x;
  if (i < E_EDGES) atomicAdd(&cnt16[c*M_NODES + dst[i]], 1);
  if (i < M_NODES){
    int g = gid[i];
    int g0 = __shfl(g, 0);
    bool lastblk = (i | 63) >= M_NODES - 1 && ((i | 63) != M_NODES - 1);
    if (__all(g == g0) && !lastblk){
      if ((threadIdx.x & 63) == 0) atomicAdd(&gcnt[g], min(64, M_NODES - (i & ~63)));
    } else {
      atomicAdd(&gcnt[g], 1);
    }
  }
}

// ---------- 3-phase exclusive scan of summed cnt16 -> rp ----------
__global__ __launch_bounds__(256) void k_scan1(const int* __restrict__ cnt16,
    int* __restrict__ rp, int* __restrict__ bsum){
  __shared__ int wsum[4];
  int b = blockIdx.x, tid = threadIdx.x, lane = tid & 63, w = tid >> 6;
  int i = b*256 + tid;
  int v = 0;
  if (i < M_NODES){
    #pragma unroll
    for (int c = 0; c < NCPY; c++) v += cnt16[c*M_NODES + i];
  }
  int x = v;
  #pragma unroll
  for (int off = 1; off < 64; off <<= 1){
    int y = __shfl_up(x, off);
    if (lane >= off) x += y;
  }
  if (lane == 63) wsum[w] = x;
  __syncthreads();
  int pre = 0;
  #pragma unroll
  for (int j = 0; j < 4; j++) if (j < w) pre += wsum[j];
  if (i < M_NODES) rp[i+1] = pre + x;
  if (tid == 255) bsum[b] = pre + x;
}

__global__ __launch_bounds__(256) void k_scan2(const int* __restrict__ bsum, int* __restrict__ boff){
  __shared__ int wsum[4];
  int tid = threadIdx.x, lane = tid & 63, w = tid >> 6;
  int v = (tid < SCAN_B) ? bsum[tid] : 0;
  int x = v;
  #pragma unroll
  for (int off = 1; off < 64; off <<= 1){
    int y = __shfl_up(x, off);
    if (lane >= off) x += y;
  }
  if (lane == 63) wsum[w] = x;
  __syncthreads();
  int pre = 0;
  #pragma unroll
  for (int j = 0; j < 4; j++) if (j < w) pre += wsum[j];
  if (tid < SCAN_B) boff[tid] = pre + x - v;
}

__global__ __launch_bounds__(256) void k_scan3(int* __restrict__ rp, const int* __restrict__ boff){
  int b = blockIdx.x, tid = threadIdx.x;
  int i = b*256 + tid;
  if (i == 0) rp[0] = 0;
  if (i < M_NODES) rp[i+1] += boff[b];
}

// ---------- per-copy segment bases ----------
__global__ __launch_bounds__(256) void k_cbase(const int* __restrict__ rp,
    const int* __restrict__ cnt16, int* __restrict__ cbase){
  int i = blockIdx.x*256 + threadIdx.x;
  if (i >= M_NODES) return;
  int base = rp[i];
  #pragma unroll
  for (int c = 0; c < NCPY; c++){
    cbase[c*M_NODES + i] = base;
    base += cnt16[c*M_NODES + i];
  }
}

// ---------- CSR fill (16-way replicated cursors) ----------
__global__ __launch_bounds__(256) void k_fill(const int* __restrict__ src,
    const int* __restrict__ dst, const int* __restrict__ cbase,
    int* __restrict__ cur16, int* __restrict__ col){
  const int c = blockIdx.x & (NCPY-1);
  int e = blockIdx.x*256 + threadIdx.x;
  if (e >= E_EDGES) return;
  int d = dst[e];
  int pos = cbase[c*M_NODES + d] + atomicAdd(&cur16[c*M_NODES + d], 1);
  col[pos] = src[e];
}

// ---------- mean aggregation, hi-only gather (256B/row), quarter-wave per node ----------
#define ACC8(u) \
  a[0] += __uint_as_float((u).x << 16); a[1] += __uint_as_float((u).x & 0xFFFF0000u); \
  a[2] += __uint_as_float((u).y << 16); a[3] += __uint_as_float((u).y & 0xFFFF0000u); \
  a[4] += __uint_as_float((u).z << 16); a[5] += __uint_as_float((u).z & 0xFFFF0000u); \
  a[6] += __uint_as_float((u).w << 16); a[7] += __uint_as_float((u).w & 0xFFFF0000u);

__global__ __launch_bounds__(256) void k_agg(const char* __restrict__ X,
    const int* __restrict__ rp, const int* __restrict__ col, char* __restrict__ G){
  const int q  = threadIdx.x >> 4;          // 16 quarters per block
  const int ql = threadIdx.x & 15;
  const int v = blockIdx.x*16 + q;
  if (v >= M_NODES) return;
  const int beg = rp[v], end = rp[v+1];
  const int off = ql*16;
  float a[8];
  #pragma unroll
  for (int k = 0; k < 8; k++) a[k] = 0.f;
  int e = beg;
  for (; e + 4 <= end; e += 4){
    const int s0 = col[e], s1 = col[e+1], s2 = col[e+2], s3 = col[e+3];
    const uint4 x0 = *reinterpret_cast<const uint4*>(X + (size_t)s0*512 + off);
    const uint4 x1 = *reinterpret_cast<const uint4*>(X + (size_t)s1*512 + off);
    const uint4 x2 = *reinterpret_cast<const uint4*>(X + (size_t)s2*512 + off);
    const uint4 x3 = *reinterpret_cast<const uint4*>(X + (size_t)s3*512 + off);
    ACC8(x0); ACC8(x1); ACC8(x2); ACC8(x3);
  }
  for (; e < end; e++){
    const uint4 x0 = *reinterpret_cast<const uint4*>(X + (size_t)col[e]*512 + off);
    ACC8(x0);
  }
  const float inv = 1.f / fmaxf((float)(end - beg), 1.f);
  uint4 hq, lq;
  unsigned hw[4], lw[4];
  #pragma unroll
  for (int k = 0; k < 4; k++){
    const float x0 = a[2*k]*inv, x1 = a[2*k+1]*inv;
    const unsigned short h0 = f2bf(x0), h1 = f2bf(x1);
    hw[k] = (unsigned)h0 | ((unsigned)h1 << 16);
    lw[k] = (unsigned)f2bf(x0 - bf2f(h0)) | ((unsigned)f2bf(x1 - bf2f(h1)) << 16);
  }
  hq.x = hw[0]; hq.y = hw[1]; hq.z = hw[2]; hq.w = hw[3];
  lq.x = lw[0]; lq.y = lw[1]; lq.z = lw[2]; lq.w = lw[3];
  *reinterpret_cast<uint4*>(G + (size_t)v*512 + off)       = hq;
  *reinterpret_cast<uint4*>(G + (size_t)v*512 + 256 + off) = lq;
}

// ---------- GEMM: split-row A (global_load_lds), split W, bf16x3 ----------
template<int KL, int NT, bool RELU, bool SPLITOUT>
__global__ __launch_bounds__(256) void k_gemm(
    const char* __restrict__ A1, const char* __restrict__ A2,
    const unsigned short* __restrict__ Wh, const unsigned short* __restrict__ Wl,
    const float* __restrict__ bias, char* __restrict__ Y){
  constexpr int NOUT = NT * 16;
  constexpr int KC = KL / 64;
  constexpr int NBI = NOUT / 32;           // B stage insts per wave
  __shared__ __align__(16) char sAh[128*128];
  __shared__ __align__(16) char sAl[128*128];
  __shared__ __align__(16) char sBh[NOUT*128];
  __shared__ __align__(16) char sBl[NOUT*128];
  const int tid = threadIdx.x;
  const int wave = tid >> 6, lane = tid & 63;
  const int blockRow = blockIdx.x * 128;
  const int srow = lane >> 3, slot = lane & 7;
  const int sb = (slot*16) ^ (srow << 4);  // inverse-swizzled source granule
  size_t aoff[4];
  #pragma unroll
  for (int i = 0; i < 4; i++){
    int grow = blockRow + wave*32 + i*8 + srow;
    if (grow >= M_NODES) grow = M_NODES - 1;
    aoff[i] = (size_t)grow*512 + sb;
  }
  size_t boff[NBI];
  #pragma unroll
  for (int i = 0; i < NBI; i++){
    int n = wave*(NOUT/4) + i*8 + srow;
    boff[i] = (size_t)n*(2*KL) + sb;
  }
  f32x4 acc[2][NT];
  #pragma unroll
  for (int a = 0; a < 2; a++)
    #pragma unroll
    for (int i = 0; i < NT; i++)
      #pragma unroll
      for (int r = 0; r < 4; r++) acc[a][i][r] = 0.f;

  for (int kc = 0; kc < KC; kc++){
    const char* Ap; int acolb;
    if (KL == 256 && kc >= 2){ Ap = A2; acolb = (kc - 2)*128; }
    else                     { Ap = A1; acolb = kc*128; }
    const int bcolb = kc*128;
    __syncthreads();
    #pragma unroll
    for (int i = 0; i < 4; i++){
      const int lr = (wave*32 + i*8)*128;
      gl_lds16(Ap + aoff[i] + acolb,       sAh + lr);
      gl_lds16(Ap + aoff[i] + acolb + 256, sAl + lr);
    }
    #pragma unroll
    for (int i = 0; i < NBI; i++){
      const int lr = (wave*(NOUT/4) + i*8)*128;
      gl_lds16(reinterpret_cast<const char*>(Wh) + boff[i] + bcolb, sBh + lr);
      gl_lds16(reinterpret_cast<const char*>(Wl) + boff[i] + bcolb, sBl + lr);
    }
    __syncthreads();
    #pragma unroll
    for (int ks = 0; ks < 2; ks++){
      const int kb = (ks*32 + ((lane >> 4) * 8)) * 2;
      bf16x8 ah[2], al[2];
      #pragma unroll
      for (int ar = 0; ar < 2; ar++){
        const int arow = wave*32 + ar*16 + (lane & 15);
        const int ab = arow*128 + (kb ^ ((arow & 7) << 4));
        ah[ar] = *reinterpret_cast<const bf16x8*>(sAh + ab);
        al[ar] = *reinterpret_cast<const bf16x8*>(sAl + ab);
      }
      #pragma unroll
      for (int nt = 0; nt < NT; nt++){
        const int n = nt*16 + (lane & 15);
        const int bb = n*128 + (kb ^ ((n & 7) << 4));
        const bf16x8 bh = *reinterpret_cast<const bf16x8*>(sBh + bb);
        const bf16x8 bl = *reinterpret_cast<const bf16x8*>(sBl + bb);
        #pragma unroll
        for (int ar = 0; ar < 2; ar++){
          acc[ar][nt] = __builtin_amdgcn_mfma_f32_16x16x32_bf16(ah[ar], bh, acc[ar][nt], 0, 0, 0);
          acc[ar][nt] = __builtin_amdgcn_mfma_f32_16x16x32_bf16(al[ar], bh, acc[ar][nt], 0, 0, 0);
          acc[ar][nt] = __builtin_amdgcn_mfma_f32_16x16x32_bf16(ah[ar], bl, acc[ar][nt], 0, 0, 0);
        }
      }
    }
  }
  // epilogue: row = (lane>>4)*4 + r, col = lane&15
  const int r0 = (lane >> 4) * 4;
  #pragma unroll
  for (int ar = 0; ar < 2; ar++){
    const int growb = blockRow + wave*32 + ar*16 + r0;
    #pragma unroll
    for (int nt = 0; nt < NT; nt++){
      const int colx = nt*16 + (lane & 15);
      const float bsv = bias[colx];
      #pragma unroll
      for (int r = 0; r < 4; r++){
        const int grow = growb + r;
        float vv = acc[ar][nt][r] + bsv;
        if (RELU) vv = fmaxf(vv, 0.f);
        if constexpr (SPLITOUT){
          const float vo = __shfl_xor(vv, 1);
          if (grow < M_NODES){
            if ((lane & 1) == 0){
              const unsigned hv = (unsigned)f2bf(vv) | ((unsigned)f2bf(vo) << 16);
              *reinterpret_cast<unsigned*>(Y + (size_t)grow*512 + colx*2) = hv;
            } else {
              const unsigned lv = (unsigned)lob(vo) | ((unsigned)lob(vv) << 16);
              *reinterpret_cast<unsigned*>(Y + (size_t)grow*512 + 256 + (colx-1)*2) = lv;
            }
          }
        } else {
          if (grow < M_NODES)
            *reinterpret_cast<float*>(Y + ((size_t)grow*NOUT + colx)*4) = vv;
        }
      }
    }
  }
}

// ---------- pooling stage 1: 8 sub-chunks per graph ----------
__global__ __launch_bounds__(256) void k_pool1(const float* __restrict__ Xf,
    const int* __restrict__ gcnt, float* __restrict__ pp){
  const int g = blockIdx.x >> 3, s = blockIdx.x & 7;
  const int tid = threadIdx.x, w = tid >> 6, lane = tid & 63;
  __shared__ int sstart;
  __shared__ float part[4][64];
  if (w == 0){
    int v = gcnt[lane];
    int x = v;
    #pragma unroll
    for (int off = 1; off < 64; off <<= 1){
      int y = __shfl_up(x, off);
      if (lane >= off) x += y;
    }
    if (lane == g) sstart = x - v;
  }
  __syncthreads();
  const int cg = gcnt[g];
  const int Lc = (cg + 7) >> 3;
  const int nbeg = sstart + s*Lc;
  const int nend = min(nbeg + Lc, sstart + cg);
  float a0 = 0.f, a1 = 0.f;
  int i = nbeg + w;
  for (; i + 4 < nend; i += 8){
    a0 += Xf[(size_t)i*64 + lane];
    a1 += Xf[(size_t)(i+4)*64 + lane];
  }
  if (i < nend) a0 += Xf[(size_t)i*64 + lane];
  part[w][lane] = a0 + a1;
  __syncthreads();
  if (w == 0)
    pp[(size_t)(g*8 + s)*64 + lane] = part[0][lane] + part[1][lane] + part[2][lane] + part[3][lane];
}

// ---------- pooling stage 2 ----------
__global__ __launch_bounds__(64) void k_pool2(const float* __restrict__ pp,
    const int* __restrict__ gcnt, float* __restrict__ out){
  const int g = blockIdx.x, lane = threadIdx.x;
  float sum = 0.f;
  #pragma unroll
  for (int s = 0; s < 8; s++) sum += pp[(size_t)(g*8 + s)*64 + lane];
  out[g*64 + lane] = sum / fmaxf((float)gcnt[g], 1.f);
}

extern "C" void kernel_launch(void* const* d_in, const int* in_sizes, int n_in,
                              void* d_out, int out_size, void* d_ws, size_t ws_size,
                              hipStream_t stream){
  const float* h    = (const float*)d_in[0];
  const int*   esrc = (const int*)d_in[1];
  const int*   edst = (const int*)d_in[2];
  const int*   gid  = (const int*)d_in[3];
  const float* ws0  = (const float*)d_in[4];
  const float* wn0  = (const float*)d_in[5];
  const float* bs0  = (const float*)d_in[6];
  const float* ws1  = (const float*)d_in[7];
  const float* wn1  = (const float*)d_in[8];
  const float* bs1  = (const float*)d_in[9];
  const float* ws2  = (const float*)d_in[10];
  const float* wn2  = (const float*)d_in[11];
  const float* bs2  = (const float*)d_in[12];
  const float* lw0  = (const float*)d_in[13];
  const float* lb0  = (const float*)d_in[14];
  const float* lw1  = (const float*)d_in[15];
  const float* lb1  = (const float*)d_in[16];
  const float* lw2  = (const float*)d_in[17];
  const float* lb2  = (const float*)d_in[18];
  float* out = (float*)d_out;

  char* p = (char*)d_ws;
  auto alloc = [&](size_t b)->char*{ char* r = p; p += (b + 255) & ~(size_t)255; return r; };
  char* X0 = alloc((size_t)M_NODES*512);
  char* XA = alloc((size_t)M_NODES*512);
  char* XB = alloc((size_t)M_NODES*512);
  char* G  = alloc((size_t)M_NODES*512);
  float* xF = (float*)alloc((size_t)M_NODES*64*4);
  float* pp = (float*)alloc((size_t)64*8*64*4);
  char* zbase = p;                       // contiguous zero-init region
  int* cnt16 = (int*)alloc((size_t)NCPY*M_NODES*4);
  int* cur16 = (int*)alloc((size_t)NCPY*M_NODES*4);
  int* gcnt  = (int*)alloc(256);
  size_t zbytes = (size_t)(p - zbase);
  int* rp    = (int*)alloc((size_t)(M_NODES+1)*4);
  int* col   = (int*)alloc((size_t)E_EDGES*4);
  int* bsum  = (int*)alloc((size_t)SCAN_B*4);
  int* boff  = (int*)alloc((size_t)SCAN_B*4);
  int* cbase = (int*)alloc((size_t)NCPY*M_NODES*4);
  unsigned short* W0h = (unsigned short*)alloc(128*256*2);
  unsigned short* W0l = (unsigned short*)alloc(128*256*2);
  unsigned short* W1h = (unsigned short*)alloc(128*256*2);
  unsigned short* W1l = (unsigned short*)alloc(128*256*2);
  unsigned short* W2h = (unsigned short*)alloc(128*256*2);
  unsigned short* W2l = (unsigned short*)alloc(128*256*2);
  unsigned short* L0h = (unsigned short*)alloc(128*128*2);
  unsigned short* L0l = (unsigned short*)alloc(128*128*2);
  unsigned short* L1h = (unsigned short*)alloc(128*128*2);
  unsigned short* L1l = (unsigned short*)alloc(128*128*2);
  unsigned short* L2h = (unsigned short*)alloc(64*128*2);
  unsigned short* L2l = (unsigned short*)alloc(64*128*2);

  hipMemsetAsync(zbase, 0, zbytes, stream);
  k_prep_all<<<544, 256, 0, stream>>>(ws0, wn0, ws1, wn1, ws2, wn2, lw0, lw1, lw2,
      W0h, W0l, W1h, W1l, W2h, W2l, L0h, L0l, L1h, L1l, L2h, L2l);
  k_split<<<(M_NODES*16 + 255)/256, 256, 0, stream>>>(h, X0);
  k_hist<<<(E_EDGES+255)/256, 256, 0, stream>>>(edst, cnt16, gid, gcnt);
  k_scan1<<<SCAN_B, 256, 0, stream>>>(cnt16, rp, bsum);
  k_scan2<<<1, 256, 0, stream>>>(bsum, boff);
  k_scan3<<<SCAN_B, 256, 0, stream>>>(rp, boff);
  k_cbase<<<SCAN_B, 256, 0, stream>>>(rp, cnt16, cbase);
  k_fill<<<(E_EDGES+255)/256, 256, 0, stream>>>(esrc, edst, cbase, cur16, col);

  const int gGrid = (M_NODES + 127)/128;
  const int aGrid = (M_NODES + 15)/16;
  // SAGE layer 0 (relu)
  k_agg<<<aGrid, 256, 0, stream>>>(X0, rp, col, G);
  k_gemm<256,8,true ,true ><<<gGrid,256,0,stream>>>(X0, G, W0h, W0l, bs0, XA);
  // SAGE layer 1 (relu)
  k_agg<<<aGrid, 256, 0, stream>>>(XA, rp, col, G);
  k_gemm<256,8,true ,true ><<<gGrid,256,0,stream>>>(XA, G, W1h, W1l, bs1, XB);
  // SAGE layer 2 (no relu)
  k_agg<<<aGrid, 256, 0, stream>>>(XB, rp, col, G);
  k_gemm<256,8,false,true ><<<gGrid,256,0,stream>>>(XB, G, W2h, W2l, bs2, XA);
  // MLP
  k_gemm<128,8,true ,true ><<<gGrid,256,0,stream>>>(XA, nullptr, L0h, L0l, lb0, XB);
  k_gemm<128,8,true ,true ><<<gGrid,256,0,stream>>>(XB, nullptr, L1h, L1l, lb1, XA);
  k_gemm<128,4,false,false><<<gGrid,256,0,stream>>>(XA, nullptr, L2h, L2l, lb2, (char*)xF);
  // pooling
  k_pool1<<<512, 256, 0, stream>>>(xF, gcnt, pp);
  k_pool2<<<64, 64, 0, stream>>>(pp, gcnt, out);
}

// Round 7
// 281.233 us; speedup vs baseline: 1.0857x; 1.0857x over previous
//
#include <hip/hip_runtime.h>

#define M_NODES 50000
#define E_EDGES 600000
#define SCAN_B ((M_NODES + 255) / 256)
#define B_H 64
#define EPB (E_EDGES / B_H)          // 9375
#define HWORDS (M_NODES / 2)         // 25000 packed u32 = 100 KB LDS

typedef short bf16x8 __attribute__((ext_vector_type(8)));
typedef float f32x4 __attribute__((ext_vector_type(4)));

__device__ __forceinline__ unsigned short f2bf(float f){
  unsigned u = __float_as_uint(f);
  u += 0x7FFFu + ((u >> 16) & 1u);
  return (unsigned short)(u >> 16);
}
__device__ __forceinline__ float bf2f(unsigned short h){
  return __uint_as_float(((unsigned)h) << 16);
}
__device__ __forceinline__ unsigned short lob(float x){
  unsigned short h = f2bf(x);
  return f2bf(x - bf2f(h));
}
__device__ __forceinline__ void gl_lds16(const void* g, void* l){
  __builtin_amdgcn_global_load_lds(
      (const __attribute__((address_space(1))) unsigned int*)g,
      (__attribute__((address_space(3))) unsigned int*)l, 16, 0, 0);
}

// ---------- split fp32 h -> split rows [hi128|lo128] ----------
__global__ __launch_bounds__(256) void k_split(const float* __restrict__ H,
    char* __restrict__ X){
  int i = blockIdx.x*256 + threadIdx.x;          // over M*16 granules
  if (i >= M_NODES*16) return;
  int n = i >> 4, j = i & 15;
  const float4 f0 = *reinterpret_cast<const float4*>(H + (size_t)n*128 + j*8);
  const float4 f1 = *reinterpret_cast<const float4*>(H + (size_t)n*128 + j*8 + 4);
  uint4 hq, lq;
  hq.x = (unsigned)f2bf(f0.x) | ((unsigned)f2bf(f0.y) << 16);
  hq.y = (unsigned)f2bf(f0.z) | ((unsigned)f2bf(f0.w) << 16);
  hq.z = (unsigned)f2bf(f1.x) | ((unsigned)f2bf(f1.y) << 16);
  hq.w = (unsigned)f2bf(f1.z) | ((unsigned)f2bf(f1.w) << 16);
  lq.x = (unsigned)lob(f0.x) | ((unsigned)lob(f0.y) << 16);
  lq.y = (unsigned)lob(f0.z) | ((unsigned)lob(f0.w) << 16);
  lq.z = (unsigned)lob(f1.x) | ((unsigned)lob(f1.y) << 16);
  lq.w = (unsigned)lob(f1.z) | ((unsigned)lob(f1.w) << 16);
  *reinterpret_cast<uint4*>(X + (size_t)n*512 + j*16)       = hq;
  *reinterpret_cast<uint4*>(X + (size_t)n*512 + 256 + j*16) = lq;
}

// ---------- all weight preps in one kernel ----------
__global__ __launch_bounds__(256) void k_prep_all(
    const float* __restrict__ ws0, const float* __restrict__ wn0,
    const float* __restrict__ ws1, const float* __restrict__ wn1,
    const float* __restrict__ ws2, const float* __restrict__ wn2,
    const float* __restrict__ lw0, const float* __restrict__ lw1,
    const float* __restrict__ lw2,
    unsigned short* __restrict__ W0h, unsigned short* __restrict__ W0l,
    unsigned short* __restrict__ W1h, unsigned short* __restrict__ W1l,
    unsigned short* __restrict__ W2h, unsigned short* __restrict__ W2l,
    unsigned short* __restrict__ L0h, unsigned short* __restrict__ L0l,
    unsigned short* __restrict__ L1h, unsigned short* __restrict__ L1l,
    unsigned short* __restrict__ L2h, unsigned short* __restrict__ L2l){
  const int b = blockIdx.x, t = threadIdx.x;
  if (b < 384){                      // stacked [ws;wn] -> [N=128][K=256]
    const int wsel = b >> 7;
    const int i = (b & 127)*256 + t;
    const float* Wa = wsel==0?ws0:(wsel==1?ws1:ws2);
    const float* Wb = wsel==0?wn0:(wsel==1?wn1:wn2);
    unsigned short* Th = wsel==0?W0h:(wsel==1?W1h:W2h);
    unsigned short* Tl = wsel==0?W0l:(wsel==1?W1l:W2l);
    int n = i >> 8, k = i & 255;
    float v = (k < 128) ? Wa[k*128 + n] : Wb[(k-128)*128 + n];
    unsigned short hi = f2bf(v);
    Th[n*256 + k] = hi; Tl[n*256 + k] = f2bf(v - bf2f(hi));
  } else if (b < 512){               // lw0/lw1 [128][128] -> [128][128]^T
    const int lsel = (b - 384) >> 6;
    const int i = ((b - 384) & 63)*256 + t;
    const float* W = lsel==0?lw0:lw1;
    unsigned short* Th = lsel==0?L0h:L1h;
    unsigned short* Tl = lsel==0?L0l:L1l;
    int n = i >> 7, k = i & 127;
    float v = W[k*128 + n];
    unsigned short hi = f2bf(v);
    Th[n*128 + k] = hi; Tl[n*128 + k] = f2bf(v - bf2f(hi));
  } else {                           // lw2 [128][64] -> [64][128]^T
    const int i = (b - 512)*256 + t;
    if (i >= 64*128) return;
    int n = i >> 7, k = i & 127;
    float v = lw2[k*64 + n];
    unsigned short hi = f2bf(v);
    L2h[n*128 + k] = hi; L2l[n*128 + k] = f2bf(v - bf2f(hi));
  }
}

// ---------- degree histogram: LDS-privatized, packed 2xu16, no global atomics ----------
__global__ __launch_bounds__(256) void k_hist(const int* __restrict__ dst,
    unsigned* __restrict__ part){
  extern __shared__ unsigned lds[];
  const int b = blockIdx.x, tid = threadIdx.x;
  uint4* lds4 = reinterpret_cast<uint4*>(lds);
  for (int j = tid; j < HWORDS/4; j += 256) lds4[j] = make_uint4(0u,0u,0u,0u);
  __syncthreads();
  const int beg = b*EPB, end = beg + EPB;
  for (int e = beg + tid; e < end; e += 256){
    const int d = dst[e];
    atomicAdd(&lds[d >> 1], 1u << ((d & 1)*16));
  }
  __syncthreads();
  unsigned* prow = part + (size_t)b*HWORDS;
  for (int j = tid; j < HWORDS; j += 256) prow[j] = lds[j];
}

// ---------- 3-phase exclusive scan over summed partials -> rp ----------
__global__ __launch_bounds__(256) void k_scan1(const unsigned* __restrict__ part,
    int* __restrict__ rp, int* __restrict__ bsum){
  __shared__ int wsum[4];
  int b = blockIdx.x, tid = threadIdx.x, lane = tid & 63, w = tid >> 6;
  int i = b*256 + tid;
  int v = 0;
  if (i < M_NODES){
    const int word = i >> 1, sh = (i & 1)*16;
    for (int c = 0; c < B_H; c++)
      v += (part[(size_t)c*HWORDS + word] >> sh) & 0xffffu;
  }
  int x = v;
  #pragma unroll
  for (int off = 1; off < 64; off <<= 1){
    int y = __shfl_up(x, off);
    if (lane >= off) x += y;
  }
  if (lane == 63) wsum[w] = x;
  __syncthreads();
  int pre = 0;
  #pragma unroll
  for (int j = 0; j < 4; j++) if (j < w) pre += wsum[j];
  if (i < M_NODES) rp[i+1] = pre + x;
  if (tid == 255) bsum[b] = pre + x;
}

__global__ __launch_bounds__(256) void k_scan2(const int* __restrict__ bsum, int* __restrict__ boff){
  __shared__ int wsum[4];
  int tid = threadIdx.x, lane = tid & 63, w = tid >> 6;
  int v = (tid < SCAN_B) ? bsum[tid] : 0;
  int x = v;
  #pragma unroll
  for (int off = 1; off < 64; off <<= 1){
    int y = __shfl_up(x, off);
    if (lane >= off) x += y;
  }
  if (lane == 63) wsum[w] = x;
  __syncthreads();
  int pre = 0;
  #pragma unroll
  for (int j = 0; j < 4; j++) if (j < w) pre += wsum[j];
  if (tid < SCAN_B) boff[tid] = pre + x - v;
}

__global__ __launch_bounds__(256) void k_scan3(int* __restrict__ rp, const int* __restrict__ boff){
  int b = blockIdx.x, tid = threadIdx.x;
  int i = b*256 + tid;
  if (i == 0) rp[0] = 0;
  if (i < M_NODES) rp[i+1] += boff[b];
}

// ---------- per-block segment bases + gid histogram (run-length, few atomics) ----------
__global__ __launch_bounds__(256) void k_cbase(const int* __restrict__ rp,
    const unsigned* __restrict__ part, int* __restrict__ cbase,
    const int* __restrict__ gid, int* __restrict__ gcnt){
  const int i = blockIdx.x*256 + threadIdx.x;
  const bool valid = i < M_NODES;
  const int lane = threadIdx.x & 63;
  // gid run-length histogram (gid is sorted)
  {
    int g = valid ? gid[i] : -1;
    int gp = __shfl_up(g, 1);
    bool bnd = valid && (lane == 0 || g != gp);
    unsigned long long mbnd = __ballot(bnd);
    unsigned long long mval = __ballot(valid);
    if (bnd){
      unsigned long long above = (lane == 63) ? 0ull : (mbnd >> (lane+1));
      int nxt = above ? (lane + 1 + (__ffsll((long long)above) - 1)) : 64;
      int lastvalid = 63 - __clzll((long long)mval);
      int runend = min(nxt, lastvalid + 1);
      atomicAdd(&gcnt[g], runend - lane);
    }
  }
  if (!valid) return;
  const int word = i >> 1, sh = (i & 1)*16;
  int base = rp[i];
  for (int c = 0; c < B_H; c++){
    cbase[(size_t)c*M_NODES + i] = base;
    base += (part[(size_t)c*HWORDS + word] >> sh) & 0xffffu;
  }
}

// ---------- CSR fill: LDS rank counters, no global atomics ----------
__global__ __launch_bounds__(256) void k_fill(const int* __restrict__ src,
    const int* __restrict__ dst, const int* __restrict__ cbase,
    int* __restrict__ col){
  extern __shared__ unsigned lds[];
  const int b = blockIdx.x, tid = threadIdx.x;
  uint4* lds4 = reinterpret_cast<uint4*>(lds);
  for (int j = tid; j < HWORDS/4; j += 256) lds4[j] = make_uint4(0u,0u,0u,0u);
  __syncthreads();
  const int beg = b*EPB, end = beg + EPB;
  const int* cb = cbase + (size_t)b*M_NODES;
  for (int e = beg + tid; e < end; e += 256){
    const int d = dst[e];
    const int sh = (d & 1)*16;
    const unsigned old = atomicAdd(&lds[d >> 1], 1u << sh);
    const int rank = (old >> sh) & 0xffffu;
    col[cb[d] + rank] = src[e];
  }
}

// ---------- mean aggregation, hi-only gather (256B/row), quarter-wave per node ----------
#define ACC8(u) \
  a[0] += __uint_as_float((u).x << 16); a[1] += __uint_as_float((u).x & 0xFFFF0000u); \
  a[2] += __uint_as_float((u).y << 16); a[3] += __uint_as_float((u).y & 0xFFFF0000u); \
  a[4] += __uint_as_float((u).z << 16); a[5] += __uint_as_float((u).z & 0xFFFF0000u); \
  a[6] += __uint_as_float((u).w << 16); a[7] += __uint_as_float((u).w & 0xFFFF0000u);

__global__ __launch_bounds__(256) void k_agg(const char* __restrict__ X,
    const int* __restrict__ rp, const int* __restrict__ col, char* __restrict__ G){
  const int q  = threadIdx.x >> 4;          // 16 quarters per block
  const int ql = threadIdx.x & 15;
  const int v = blockIdx.x*16 + q;
  if (v >= M_NODES) return;
  const int beg = rp[v], end = rp[v+1];
  const int off = ql*16;
  float a[8];
  #pragma unroll
  for (int k = 0; k < 8; k++) a[k] = 0.f;
  int e = beg;
  for (; e + 4 <= end; e += 4){
    const int s0 = col[e], s1 = col[e+1], s2 = col[e+2], s3 = col[e+3];
    const uint4 x0 = *reinterpret_cast<const uint4*>(X + (size_t)s0*512 + off);
    const uint4 x1 = *reinterpret_cast<const uint4*>(X + (size_t)s1*512 + off);
    const uint4 x2 = *reinterpret_cast<const uint4*>(X + (size_t)s2*512 + off);
    const uint4 x3 = *reinterpret_cast<const uint4*>(X + (size_t)s3*512 + off);
    ACC8(x0); ACC8(x1); ACC8(x2); ACC8(x3);
  }
  for (; e < end; e++){
    const uint4 x0 = *reinterpret_cast<const uint4*>(X + (size_t)col[e]*512 + off);
    ACC8(x0);
  }
  const float inv = 1.f / fmaxf((float)(end - beg), 1.f);
  uint4 hq, lq;
  unsigned hw[4], lw[4];
  #pragma unroll
  for (int k = 0; k < 4; k++){
    const float x0 = a[2*k]*inv, x1 = a[2*k+1]*inv;
    const unsigned short h0 = f2bf(x0), h1 = f2bf(x1);
    hw[k] = (unsigned)h0 | ((unsigned)h1 << 16);
    lw[k] = (unsigned)f2bf(x0 - bf2f(h0)) | ((unsigned)f2bf(x1 - bf2f(h1)) << 16);
  }
  hq.x = hw[0]; hq.y = hw[1]; hq.z = hw[2]; hq.w = hw[3];
  lq.x = lw[0]; lq.y = lw[1]; lq.z = lw[2]; lq.w = lw[3];
  *reinterpret_cast<uint4*>(G + (size_t)v*512 + off)       = hq;
  *reinterpret_cast<uint4*>(G + (size_t)v*512 + 256 + off) = lq;
}

// ---------- GEMM: split-row A (global_load_lds), split W, bf16x3 ----------
template<int KL, int NT, bool RELU, bool SPLITOUT>
__global__ __launch_bounds__(256) void k_gemm(
    const char* __restrict__ A1, const char* __restrict__ A2,
    const unsigned short* __restrict__ Wh, const unsigned short* __restrict__ Wl,
    const float* __restrict__ bias, char* __restrict__ Y){
  constexpr int NOUT = NT * 16;
  constexpr int KC = KL / 64;
  constexpr int NBI = NOUT / 32;           // B stage insts per wave
  __shared__ __align__(16) char sAh[128*128];
  __shared__ __align__(16) char sAl[128*128];
  __shared__ __align__(16) char sBh[NOUT*128];
  __shared__ __align__(16) char sBl[NOUT*128];
  const int tid = threadIdx.x;
  const int wave = tid >> 6, lane = tid & 63;
  const int blockRow = blockIdx.x * 128;
  const int srow = lane >> 3, slot = lane & 7;
  const int sb = (slot*16) ^ (srow << 4);  // inverse-swizzled source granule
  size_t aoff[4];
  #pragma unroll
  for (int i = 0; i < 4; i++){
    int grow = blockRow + wave*32 + i*8 + srow;
    if (grow >= M_NODES) grow = M_NODES - 1;
    aoff[i] = (size_t)grow*512 + sb;
  }
  size_t boff[NBI];
  #pragma unroll
  for (int i = 0; i < NBI; i++){
    int n = wave*(NOUT/4) + i*8 + srow;
    boff[i] = (size_t)n*(2*KL) + sb;
  }
  f32x4 acc[2][NT];
  #pragma unroll
  for (int a = 0; a < 2; a++)
    #pragma unroll
    for (int i = 0; i < NT; i++)
      #pragma unroll
      for (int r = 0; r < 4; r++) acc[a][i][r] = 0.f;

  for (int kc = 0; kc < KC; kc++){
    const char* Ap; int acolb;
    if (KL == 256 && kc >= 2){ Ap = A2; acolb = (kc - 2)*128; }
    else                     { Ap = A1; acolb = kc*128; }
    const int bcolb = kc*128;
    __syncthreads();
    #pragma unroll
    for (int i = 0; i < 4; i++){
      const int lr = (wave*32 + i*8)*128;
      gl_lds16(Ap + aoff[i] + acolb,       sAh + lr);
      gl_lds16(Ap + aoff[i] + acolb + 256, sAl + lr);
    }
    #pragma unroll
    for (int i = 0; i < NBI; i++){
      const int lr = (wave*(NOUT/4) + i*8)*128;
      gl_lds16(reinterpret_cast<const char*>(Wh) + boff[i] + bcolb, sBh + lr);
      gl_lds16(reinterpret_cast<const char*>(Wl) + boff[i] + bcolb, sBl + lr);
    }
    __syncthreads();
    #pragma unroll
    for (int ks = 0; ks < 2; ks++){
      const int kb = (ks*32 + ((lane >> 4) * 8)) * 2;
      bf16x8 ah[2], al[2];
      #pragma unroll
      for (int ar = 0; ar < 2; ar++){
        const int arow = wave*32 + ar*16 + (lane & 15);
        const int ab = arow*128 + (kb ^ ((arow & 7) << 4));
        ah[ar] = *reinterpret_cast<const bf16x8*>(sAh + ab);
        al[ar] = *reinterpret_cast<const bf16x8*>(sAl + ab);
      }
      #pragma unroll
      for (int nt = 0; nt < NT; nt++){
        const int n = nt*16 + (lane & 15);
        const int bb = n*128 + (kb ^ ((n & 7) << 4));
        const bf16x8 bh = *reinterpret_cast<const bf16x8*>(sBh + bb);
        const bf16x8 bl = *reinterpret_cast<const bf16x8*>(sBl + bb);
        #pragma unroll
        for (int ar = 0; ar < 2; ar++){
          acc[ar][nt] = __builtin_amdgcn_mfma_f32_16x16x32_bf16(ah[ar], bh, acc[ar][nt], 0, 0, 0);
          acc[ar][nt] = __builtin_amdgcn_mfma_f32_16x16x32_bf16(al[ar], bh, acc[ar][nt], 0, 0, 0);
          acc[ar][nt] = __builtin_amdgcn_mfma_f32_16x16x32_bf16(ah[ar], bl, acc[ar][nt], 0, 0, 0);
        }
      }
    }
  }
  // epilogue: row = (lane>>4)*4 + r, col = lane&15
  const int r0 = (lane >> 4) * 4;
  #pragma unroll
  for (int ar = 0; ar < 2; ar++){
    const int growb = blockRow + wave*32 + ar*16 + r0;
    #pragma unroll
    for (int nt = 0; nt < NT; nt++){
      const int colx = nt*16 + (lane & 15);
      const float bsv = bias[colx];
      #pragma unroll
      for (int r = 0; r < 4; r++){
        const int grow = growb + r;
        float vv = acc[ar][nt][r] + bsv;
        if (RELU) vv = fmaxf(vv, 0.f);
        if constexpr (SPLITOUT){
          const float vo = __shfl_xor(vv, 1);
          if (grow < M_NODES){
            if ((lane & 1) == 0){
              const unsigned hv = (unsigned)f2bf(vv) | ((unsigned)f2bf(vo) << 16);
              *reinterpret_cast<unsigned*>(Y + (size_t)grow*512 + colx*2) = hv;
            } else {
              const unsigned lv = (unsigned)lob(vo) | ((unsigned)lob(vv) << 16);
              *reinterpret_cast<unsigned*>(Y + (size_t)grow*512 + 256 + (colx-1)*2) = lv;
            }
          }
        } else {
          if (grow < M_NODES)
            *reinterpret_cast<float*>(Y + ((size_t)grow*NOUT + colx)*4) = vv;
        }
      }
    }
  }
}

// ---------- pooling stage 1: 8 sub-chunks per graph ----------
__global__ __launch_bounds__(256) void k_pool1(const float* __restrict__ Xf,
    const int* __restrict__ gcnt, float* __restrict__ pp){
  const int g = blockIdx.x >> 3, s = blockIdx.x & 7;
  const int tid = threadIdx.x, w = tid >> 6, lane = tid & 63;
  __shared__ int sstart;
  __shared__ float part[4][64];
  if (w == 0){
    int v = gcnt[lane];
    int x = v;
    #pragma unroll
    for (int off = 1; off < 64; off <<= 1){
      int y = __shfl_up(x, off);
      if (lane >= off) x += y;
    }
    if (lane == g) sstart = x - v;
  }
  __syncthreads();
  const int cg = gcnt[g];
  const int Lc = (cg + 7) >> 3;
  const int nbeg = sstart + s*Lc;
  const int nend = min(nbeg + Lc, sstart + cg);
  float a0 = 0.f, a1 = 0.f;
  int i = nbeg + w;
  for (; i + 4 < nend; i += 8){
    a0 += Xf[(size_t)i*64 + lane];
    a1 += Xf[(size_t)(i+4)*64 + lane];
  }
  if (i < nend) a0 += Xf[(size_t)i*64 + lane];
  part[w][lane] = a0 + a1;
  __syncthreads();
  if (w == 0)
    pp[(size_t)(g*8 + s)*64 + lane] = part[0][lane] + part[1][lane] + part[2][lane] + part[3][lane];
}

// ---------- pooling stage 2 ----------
__global__ __launch_bounds__(64) void k_pool2(const float* __restrict__ pp,
    const int* __restrict__ gcnt, float* __restrict__ out){
  const int g = blockIdx.x, lane = threadIdx.x;
  float sum = 0.f;
  #pragma unroll
  for (int s = 0; s < 8; s++) sum += pp[(size_t)(g*8 + s)*64 + lane];
  out[g*64 + lane] = sum / fmaxf((float)gcnt[g], 1.f);
}

extern "C" void kernel_launch(void* const* d_in, const int* in_sizes, int n_in,
                              void* d_out, int out_size, void* d_ws, size_t ws_size,
                              hipStream_t stream){
  const float* h    = (const float*)d_in[0];
  const int*   esrc = (const int*)d_in[1];
  const int*   edst = (const int*)d_in[2];
  const int*   gid  = (const int*)d_in[3];
  const float* ws0  = (const float*)d_in[4];
  const float* wn0  = (const float*)d_in[5];
  const float* bs0  = (const float*)d_in[6];
  const float* ws1  = (const float*)d_in[7];
  const float* wn1  = (const float*)d_in[8];
  const float* bs1  = (const float*)d_in[9];
  const float* ws2  = (const float*)d_in[10];
  const float* wn2  = (const float*)d_in[11];
  const float* bs2  = (const float*)d_in[12];
  const float* lw0  = (const float*)d_in[13];
  const float* lb0  = (const float*)d_in[14];
  const float* lw1  = (const float*)d_in[15];
  const float* lb1  = (const float*)d_in[16];
  const float* lw2  = (const float*)d_in[17];
  const float* lb2  = (const float*)d_in[18];
  float* out = (float*)d_out;

  char* p = (char*)d_ws;
  auto alloc = [&](size_t b)->char*{ char* r = p; p += (b + 255) & ~(size_t)255; return r; };
  char* X0 = alloc((size_t)M_NODES*512);
  char* XA = alloc((size_t)M_NODES*512);
  char* XB = alloc((size_t)M_NODES*512);
  char* G  = alloc((size_t)M_NODES*512);
  float* xF = (float*)alloc((size_t)M_NODES*64*4);
  float* pp = (float*)alloc((size_t)64*8*64*4);
  char* zbase = p;                       // contiguous zero-init region
  int* gcnt  = (int*)alloc(256);
  size_t zbytes = (size_t)(p - zbase);
  unsigned* part = (unsigned*)alloc((size_t)B_H*HWORDS*4);
  int* cbase = (int*)alloc((size_t)B_H*M_NODES*4);
  int* rp    = (int*)alloc((size_t)(M_NODES+1)*4);
  int* col   = (int*)alloc((size_t)E_EDGES*4);
  int* bsum  = (int*)alloc((size_t)SCAN_B*4);
  int* boff  = (int*)alloc((size_t)SCAN_B*4);
  unsigned short* W0h = (unsigned short*)alloc(128*256*2);
  unsigned short* W0l = (unsigned short*)alloc(128*256*2);
  unsigned short* W1h = (unsigned short*)alloc(128*256*2);
  unsigned short* W1l = (unsigned short*)alloc(128*256*2);
  unsigned short* W2h = (unsigned short*)alloc(128*256*2);
  unsigned short* W2l = (unsigned short*)alloc(128*256*2);
  unsigned short* L0h = (unsigned short*)alloc(128*128*2);
  unsigned short* L0l = (unsigned short*)alloc(128*128*2);
  unsigned short* L1h = (unsigned short*)alloc(128*128*2);
  unsigned short* L1l = (unsigned short*)alloc(128*128*2);
  unsigned short* L2h = (unsigned short*)alloc(64*128*2);
  unsigned short* L2l = (unsigned short*)alloc(64*128*2);

  hipMemsetAsync(zbase, 0, zbytes, stream);
  k_prep_all<<<544, 256, 0, stream>>>(ws0, wn0, ws1, wn1, ws2, wn2, lw0, lw1, lw2,
      W0h, W0l, W1h, W1l, W2h, W2l, L0h, L0l, L1h, L1l, L2h, L2l);
  k_split<<<(M_NODES*16 + 255)/256, 256, 0, stream>>>(h, X0);
  k_hist<<<B_H, 256, HWORDS*4, stream>>>(edst, part);
  k_scan1<<<SCAN_B, 256, 0, stream>>>(part, rp, bsum);
  k_scan2<<<1, 256, 0, stream>>>(bsum, boff);
  k_scan3<<<SCAN_B, 256, 0, stream>>>(rp, boff);
  k_cbase<<<SCAN_B, 256, 0, stream>>>(rp, part, cbase, gid, gcnt);
  k_fill<<<B_H, 256, HWORDS*4, stream>>>(esrc, edst, cbase, col);

  const int gGrid = (M_NODES + 127)/128;
  const int aGrid = (M_NODES + 15)/16;
  // SAGE layer 0 (relu)
  k_agg<<<aGrid, 256, 0, stream>>>(X0, rp, col, G);
  k_gemm<256,8,true ,true ><<<gGrid,256,0,stream>>>(X0, G, W0h, W0l, bs0, XA);
  // SAGE layer 1 (relu)
  k_agg<<<aGrid, 256, 0, stream>>>(XA, rp, col, G);
  k_gemm<256,8,true ,true ><<<gGrid,256,0,stream>>>(XA, G, W1h, W1l, bs1, XB);
  // SAGE layer 2 (no relu)
  k_agg<<<aGrid, 256, 0, stream>>>(XB, rp, col, G);
  k_gemm<256,8,false,true ><<<gGrid,256,0,stream>>>(XB, G, W2h, W2l, bs2, XA);
  // MLP
  k_gemm<128,8,true ,true ><<<gGrid,256,0,stream>>>(XA, nullptr, L0h, L0l, lb0, XB);
  k_gemm<128,8,true ,true ><<<gGrid,256,0,stream>>>(XB, nullptr, L1h, L1l, lb1, XA);
  k_gemm<128,4,false,false><<<gGrid,256,0,stream>>>(XA, nullptr, L2h, L2l, lb2, (char*)xF);
  // pooling
  k_pool1<<<512, 256, 0, stream>>>(xF, gcnt, pp);
  k_pool2<<<64, 64, 0, stream>>>(pp, gcnt, out);
}

// Round 8
// 224.015 us; speedup vs baseline: 1.3630x; 1.2554x over previous
//
#include <hip/hip_runtime.h>

#define M_NODES 50000
#define E_EDGES 600000
#define SCAN_B ((M_NODES + 255) / 256)
#define B_H 64
#define EPB (E_EDGES / B_H)          // 9375
#define HWORDS (M_NODES / 2)         // 25000 packed u32 = 100 KB LDS

typedef short bf16x8 __attribute__((ext_vector_type(8)));
typedef float f32x4 __attribute__((ext_vector_type(4)));

__device__ __forceinline__ unsigned short f2bf(float f){
  unsigned u = __float_as_uint(f);
  u += 0x7FFFu + ((u >> 16) & 1u);
  return (unsigned short)(u >> 16);
}
__device__ __forceinline__ float bf2f(unsigned short h){
  return __uint_as_float(((unsigned)h) << 16);
}
__device__ __forceinline__ void gl_lds16(const void* g, void* l){
  __builtin_amdgcn_global_load_lds(
      (const __attribute__((address_space(1))) unsigned int*)g,
      (__attribute__((address_space(3))) unsigned int*)l, 16, 0, 0);
}

// ---------- fused: weight prep (split hi/lo, transposed) + activation split (pure bf16) ----------
__global__ __launch_bounds__(256) void k_prep(
    const float* __restrict__ ws0, const float* __restrict__ wn0,
    const float* __restrict__ ws1, const float* __restrict__ wn1,
    const float* __restrict__ ws2, const float* __restrict__ wn2,
    const float* __restrict__ lw0, const float* __restrict__ lw1,
    const float* __restrict__ lw2, const float* __restrict__ H,
    unsigned short* __restrict__ W0h, unsigned short* __restrict__ W0l,
    unsigned short* __restrict__ W1h, unsigned short* __restrict__ W1l,
    unsigned short* __restrict__ W2h, unsigned short* __restrict__ W2l,
    unsigned short* __restrict__ L0h, unsigned short* __restrict__ L0l,
    unsigned short* __restrict__ L1h, unsigned short* __restrict__ L1l,
    unsigned short* __restrict__ L2h, unsigned short* __restrict__ L2l,
    char* __restrict__ X){
  const int b = blockIdx.x, t = threadIdx.x;
  if (b < 384){                      // stacked [ws;wn] -> [N=128][K=256]
    const int wsel = b >> 7;
    const int i = (b & 127)*256 + t;
    const float* Wa = wsel==0?ws0:(wsel==1?ws1:ws2);
    const float* Wb = wsel==0?wn0:(wsel==1?wn1:wn2);
    unsigned short* Th = wsel==0?W0h:(wsel==1?W1h:W2h);
    unsigned short* Tl = wsel==0?W0l:(wsel==1?W1l:W2l);
    int n = i >> 8, k = i & 255;
    float v = (k < 128) ? Wa[k*128 + n] : Wb[(k-128)*128 + n];
    unsigned short hi = f2bf(v);
    Th[n*256 + k] = hi; Tl[n*256 + k] = f2bf(v - bf2f(hi));
  } else if (b < 512){               // lw0/lw1 [128][128] -> [128][128]^T
    const int lsel = (b - 384) >> 6;
    const int i = ((b - 384) & 63)*256 + t;
    const float* W = lsel==0?lw0:lw1;
    unsigned short* Th = lsel==0?L0h:L1h;
    unsigned short* Tl = lsel==0?L0l:L1l;
    int n = i >> 7, k = i & 127;
    float v = W[k*128 + n];
    unsigned short hi = f2bf(v);
    Th[n*128 + k] = hi; Tl[n*128 + k] = f2bf(v - bf2f(hi));
  } else if (b < 544){               // lw2 [128][64] -> [64][128]^T
    const int i = (b - 512)*256 + t;
    if (i >= 64*128) return;
    int n = i >> 7, k = i & 127;
    float v = lw2[k*64 + n];
    unsigned short hi = f2bf(v);
    L2h[n*128 + k] = hi; L2l[n*128 + k] = f2bf(v - bf2f(hi));
  } else {                           // split h -> pure-bf16 rows (256B)
    const int i = (b - 544)*256 + t; // over M*16 granules of 16B
    if (i >= M_NODES*16) return;
    const int n = i >> 4, j = i & 15;
    const float4 f0 = *reinterpret_cast<const float4*>(H + (size_t)n*128 + j*8);
    const float4 f1 = *reinterpret_cast<const float4*>(H + (size_t)n*128 + j*8 + 4);
    uint4 hq;
    hq.x = (unsigned)f2bf(f0.x) | ((unsigned)f2bf(f0.y) << 16);
    hq.y = (unsigned)f2bf(f0.z) | ((unsigned)f2bf(f0.w) << 16);
    hq.z = (unsigned)f2bf(f1.x) | ((unsigned)f2bf(f1.y) << 16);
    hq.w = (unsigned)f2bf(f1.z) | ((unsigned)f2bf(f1.w) << 16);
    *reinterpret_cast<uint4*>(X + (size_t)n*256 + j*16) = hq;
  }
}

// ---------- degree histogram: LDS-privatized, packed 2xu16, no global atomics ----------
__global__ __launch_bounds__(256) void k_hist(const int* __restrict__ dst,
    unsigned* __restrict__ part){
  extern __shared__ unsigned lds[];
  const int b = blockIdx.x, tid = threadIdx.x;
  uint4* lds4 = reinterpret_cast<uint4*>(lds);
  for (int j = tid; j < HWORDS/4; j += 256) lds4[j] = make_uint4(0u,0u,0u,0u);
  __syncthreads();
  const int beg = b*EPB, end = beg + EPB;
  for (int e = beg + tid; e < end; e += 256){
    const int d = dst[e];
    atomicAdd(&lds[d >> 1], 1u << ((d & 1)*16));
  }
  __syncthreads();
  unsigned* prow = part + (size_t)b*HWORDS;
  for (int j = tid; j < HWORDS; j += 256) prow[j] = lds[j];
}

// ---------- scan phase 1: block-local prefix over summed partials ----------
__global__ __launch_bounds__(256) void k_scan1(const unsigned* __restrict__ part,
    int* __restrict__ rp, int* __restrict__ bsum){
  __shared__ int wsum[4];
  int b = blockIdx.x, tid = threadIdx.x, lane = tid & 63, w = tid >> 6;
  int i = b*256 + tid;
  int v = 0;
  if (i < M_NODES){
    const int word = i >> 1, sh = (i & 1)*16;
    for (int c = 0; c < B_H; c++)
      v += (part[(size_t)c*HWORDS + word] >> sh) & 0xffffu;
  }
  int x = v;
  #pragma unroll
  for (int off = 1; off < 64; off <<= 1){
    int y = __shfl_up(x, off);
    if (lane >= off) x += y;
  }
  if (lane == 63) wsum[w] = x;
  __syncthreads();
  int pre = 0;
  #pragma unroll
  for (int j = 0; j < 4; j++) if (j < w) pre += wsum[j];
  if (i < M_NODES) rp[i+1] = pre + x;
  if (tid == 255) bsum[b] = pre + x;
}

__global__ __launch_bounds__(256) void k_scan2(const int* __restrict__ bsum, int* __restrict__ boff){
  __shared__ int wsum[4];
  int tid = threadIdx.x, lane = tid & 63, w = tid >> 6;
  int v = (tid < SCAN_B) ? bsum[tid] : 0;
  int x = v;
  #pragma unroll
  for (int off = 1; off < 64; off <<= 1){
    int y = __shfl_up(x, off);
    if (lane >= off) x += y;
  }
  if (lane == 63) wsum[w] = x;
  __syncthreads();
  int pre = 0;
  #pragma unroll
  for (int j = 0; j < 4; j++) if (j < w) pre += wsum[j];
  if (tid < SCAN_B) boff[tid] = pre + x - v;
}

// ---------- finalize rp (scan3) + per-block segment bases + gid histogram ----------
__global__ __launch_bounds__(256) void k_cbase(int* __restrict__ rp,
    const int* __restrict__ boff, const unsigned* __restrict__ part,
    int* __restrict__ cbase, const int* __restrict__ gid, int* __restrict__ gcnt){
  const int b = blockIdx.x, tid = threadIdx.x;
  const int i = b*256 + tid;
  const bool valid = i < M_NODES;
  const int lane = tid & 63;
  // read local prefixes before overwriting (block-local race avoided by sync)
  const int lp = (tid == 0) ? 0 : (valid ? rp[i] : 0);          // local exclusive at i
  const int li = valid ? rp[i+1] : 0;                           // local inclusive
  __syncthreads();
  const int bo = boff[b];
  if (valid) rp[i+1] = li + bo;
  if (i == 0) rp[0] = 0;
  // gid run-length histogram (gid is sorted)
  {
    int g = valid ? gid[i] : -1;
    int gp = __shfl_up(g, 1);
    bool bnd = valid && (lane == 0 || g != gp);
    unsigned long long mbnd = __ballot(bnd);
    unsigned long long mval = __ballot(valid);
    if (bnd){
      unsigned long long above = (lane == 63) ? 0ull : (mbnd >> (lane+1));
      int nxt = above ? (lane + 1 + (__ffsll((long long)above) - 1)) : 64;
      int lastvalid = 63 - __clzll((long long)mval);
      int runend = min(nxt, lastvalid + 1);
      atomicAdd(&gcnt[g], runend - lane);
    }
  }
  if (!valid) return;
  const int word = i >> 1, sh = (i & 1)*16;
  int base = lp + bo;
  for (int c = 0; c < B_H; c++){
    cbase[(size_t)c*M_NODES + i] = base;
    base += (part[(size_t)c*HWORDS + word] >> sh) & 0xffffu;
  }
}

// ---------- CSR fill: LDS rank counters, no global atomics ----------
__global__ __launch_bounds__(256) void k_fill(const int* __restrict__ src,
    const int* __restrict__ dst, const int* __restrict__ cbase,
    int* __restrict__ col){
  extern __shared__ unsigned lds[];
  const int b = blockIdx.x, tid = threadIdx.x;
  uint4* lds4 = reinterpret_cast<uint4*>(lds);
  for (int j = tid; j < HWORDS/4; j += 256) lds4[j] = make_uint4(0u,0u,0u,0u);
  __syncthreads();
  const int beg = b*EPB, end = beg + EPB;
  const int* cb = cbase + (size_t)b*M_NODES;
  for (int e = beg + tid; e < end; e += 256){
    const int d = dst[e];
    const int sh = (d & 1)*16;
    const unsigned old = atomicAdd(&lds[d >> 1], 1u << sh);
    const int rank = (old >> sh) & 0xffffu;
    col[cb[d] + rank] = src[e];
  }
}

// ---------- mean aggregation over pure-bf16 rows (256B), quarter-wave per node ----------
#define ACC8(u) \
  a[0] += __uint_as_float((u).x << 16); a[1] += __uint_as_float((u).x & 0xFFFF0000u); \
  a[2] += __uint_as_float((u).y << 16); a[3] += __uint_as_float((u).y & 0xFFFF0000u); \
  a[4] += __uint_as_float((u).z << 16); a[5] += __uint_as_float((u).z & 0xFFFF0000u); \
  a[6] += __uint_as_float((u).w << 16); a[7] += __uint_as_float((u).w & 0xFFFF0000u);

__global__ __launch_bounds__(256) void k_agg(const char* __restrict__ X,
    const int* __restrict__ rp, const int* __restrict__ col, char* __restrict__ G){
  const int q  = threadIdx.x >> 4;          // 16 quarters per block
  const int ql = threadIdx.x & 15;
  const int v = blockIdx.x*16 + q;
  if (v >= M_NODES) return;
  const int beg = rp[v], end = rp[v+1];
  const int off = ql*16;
  float a[8];
  #pragma unroll
  for (int k = 0; k < 8; k++) a[k] = 0.f;
  int e = beg;
  for (; e + 4 <= end; e += 4){
    const int s0 = col[e], s1 = col[e+1], s2 = col[e+2], s3 = col[e+3];
    const uint4 x0 = *reinterpret_cast<const uint4*>(X + (size_t)s0*256 + off);
    const uint4 x1 = *reinterpret_cast<const uint4*>(X + (size_t)s1*256 + off);
    const uint4 x2 = *reinterpret_cast<const uint4*>(X + (size_t)s2*256 + off);
    const uint4 x3 = *reinterpret_cast<const uint4*>(X + (size_t)s3*256 + off);
    ACC8(x0); ACC8(x1); ACC8(x2); ACC8(x3);
  }
  for (; e < end; e++){
    const uint4 x0 = *reinterpret_cast<const uint4*>(X + (size_t)col[e]*256 + off);
    ACC8(x0);
  }
  const float inv = 1.f / fmaxf((float)(end - beg), 1.f);
  uint4 hq;
  unsigned hw[4];
  #pragma unroll
  for (int k = 0; k < 4; k++){
    const float x0 = a[2*k]*inv, x1 = a[2*k+1]*inv;
    hw[k] = (unsigned)f2bf(x0) | ((unsigned)f2bf(x1) << 16);
  }
  hq.x = hw[0]; hq.y = hw[1]; hq.z = hw[2]; hq.w = hw[3];
  *reinterpret_cast<uint4*>(G + (size_t)v*256 + off) = hq;
}

// ---------- GEMM: pure-bf16 A (global_load_lds), split W (hi+lo), 2 MFMAs/tile ----------
template<int KL, int NT, bool RELU, bool BF16OUT>
__global__ __launch_bounds__(256) void k_gemm(
    const char* __restrict__ A1, const char* __restrict__ A2,
    const unsigned short* __restrict__ Wh, const unsigned short* __restrict__ Wl,
    const float* __restrict__ bias, char* __restrict__ Y){
  constexpr int NOUT = NT * 16;
  constexpr int KC = KL / 64;
  constexpr int NBI = NOUT / 32;           // B stage insts per wave
  __shared__ __align__(16) char sA [128*128];
  __shared__ __align__(16) char sBh[NOUT*128];
  __shared__ __align__(16) char sBl[NOUT*128];
  const int tid = threadIdx.x;
  const int wave = tid >> 6, lane = tid & 63;
  const int blockRow = blockIdx.x * 128;
  const int srow = lane >> 3, slot = lane & 7;
  const int sb = (slot*16) ^ (srow << 4);  // inverse-swizzled source granule
  size_t aoff[4];
  #pragma unroll
  for (int i = 0; i < 4; i++){
    int grow = blockRow + wave*32 + i*8 + srow;
    if (grow >= M_NODES) grow = M_NODES - 1;
    aoff[i] = (size_t)grow*256 + sb;
  }
  size_t boff[NBI];
  #pragma unroll
  for (int i = 0; i < NBI; i++){
    int n = wave*(NOUT/4) + i*8 + srow;
    boff[i] = (size_t)n*(2*KL) + sb;
  }
  f32x4 acc[2][NT];
  #pragma unroll
  for (int a = 0; a < 2; a++)
    #pragma unroll
    for (int i = 0; i < NT; i++)
      #pragma unroll
      for (int r = 0; r < 4; r++) acc[a][i][r] = 0.f;

  for (int kc = 0; kc < KC; kc++){
    const char* Ap; int acolb;
    if (KL == 256 && kc >= 2){ Ap = A2; acolb = (kc - 2)*128; }
    else                     { Ap = A1; acolb = kc*128; }
    const int bcolb = kc*128;
    __syncthreads();
    #pragma unroll
    for (int i = 0; i < 4; i++){
      const int lr = (wave*32 + i*8)*128;
      gl_lds16(Ap + aoff[i] + acolb, sA + lr);
    }
    #pragma unroll
    for (int i = 0; i < NBI; i++){
      const int lr = (wave*(NOUT/4) + i*8)*128;
      gl_lds16(reinterpret_cast<const char*>(Wh) + boff[i] + bcolb, sBh + lr);
      gl_lds16(reinterpret_cast<const char*>(Wl) + boff[i] + bcolb, sBl + lr);
    }
    __syncthreads();
    #pragma unroll
    for (int ks = 0; ks < 2; ks++){
      const int kb = (ks*32 + ((lane >> 4) * 8)) * 2;
      bf16x8 ah[2];
      #pragma unroll
      for (int ar = 0; ar < 2; ar++){
        const int arow = wave*32 + ar*16 + (lane & 15);
        ah[ar] = *reinterpret_cast<const bf16x8*>(sA + arow*128 + (kb ^ ((arow & 7) << 4)));
      }
      #pragma unroll
      for (int nt = 0; nt < NT; nt++){
        const int n = nt*16 + (lane & 15);
        const int bb = n*128 + (kb ^ ((n & 7) << 4));
        const bf16x8 bh = *reinterpret_cast<const bf16x8*>(sBh + bb);
        const bf16x8 bl = *reinterpret_cast<const bf16x8*>(sBl + bb);
        #pragma unroll
        for (int ar = 0; ar < 2; ar++){
          acc[ar][nt] = __builtin_amdgcn_mfma_f32_16x16x32_bf16(ah[ar], bh, acc[ar][nt], 0, 0, 0);
          acc[ar][nt] = __builtin_amdgcn_mfma_f32_16x16x32_bf16(ah[ar], bl, acc[ar][nt], 0, 0, 0);
        }
      }
    }
  }
  // epilogue: row = (lane>>4)*4 + r, col = lane&15
  const int r0 = (lane >> 4) * 4;
  #pragma unroll
  for (int ar = 0; ar < 2; ar++){
    const int growb = blockRow + wave*32 + ar*16 + r0;
    #pragma unroll
    for (int nt = 0; nt < NT; nt++){
      const int colx = nt*16 + (lane & 15);
      const float bsv = bias[colx];
      #pragma unroll
      for (int r = 0; r < 4; r++){
        const int grow = growb + r;
        float vv = acc[ar][nt][r] + bsv;
        if (RELU) vv = fmaxf(vv, 0.f);
        if constexpr (BF16OUT){
          const float vo = __shfl_xor(vv, 1);
          if ((lane & 1) == 0 && grow < M_NODES){
            const unsigned hv = (unsigned)f2bf(vv) | ((unsigned)f2bf(vo) << 16);
            *reinterpret_cast<unsigned*>(Y + (size_t)grow*256 + colx*2) = hv;
          }
        } else {
          if (grow < M_NODES)
            *reinterpret_cast<float*>(Y + ((size_t)grow*NOUT + colx)*4) = vv;
        }
      }
    }
  }
}

// ---------- pooling stage 1: 8 sub-chunks per graph ----------
__global__ __launch_bounds__(256) void k_pool1(const float* __restrict__ Xf,
    const int* __restrict__ gcnt, float* __restrict__ pp){
  const int g = blockIdx.x >> 3, s = blockIdx.x & 7;
  const int tid = threadIdx.x, w = tid >> 6, lane = tid & 63;
  __shared__ int sstart;
  __shared__ float part[4][64];
  if (w == 0){
    int v = gcnt[lane];
    int x = v;
    #pragma unroll
    for (int off = 1; off < 64; off <<= 1){
      int y = __shfl_up(x, off);
      if (lane >= off) x += y;
    }
    if (lane == g) sstart = x - v;
  }
  __syncthreads();
  const int cg = gcnt[g];
  const int Lc = (cg + 7) >> 3;
  const int nbeg = sstart + s*Lc;
  const int nend = min(nbeg + Lc, sstart + cg);
  float a0 = 0.f, a1 = 0.f;
  int i = nbeg + w;
  for (; i + 4 < nend; i += 8){
    a0 += Xf[(size_t)i*64 + lane];
    a1 += Xf[(size_t)(i+4)*64 + lane];
  }
  if (i < nend) a0 += Xf[(size_t)i*64 + lane];
  part[w][lane] = a0 + a1;
  __syncthreads();
  if (w == 0)
    pp[(size_t)(g*8 + s)*64 + lane] = part[0][lane] + part[1][lane] + part[2][lane] + part[3][lane];
}

// ---------- pooling stage 2 ----------
__global__ __launch_bounds__(64) void k_pool2(const float* __restrict__ pp,
    const int* __restrict__ gcnt, float* __restrict__ out){
  const int g = blockIdx.x, lane = threadIdx.x;
  float sum = 0.f;
  #pragma unroll
  for (int s = 0; s < 8; s++) sum += pp[(size_t)(g*8 + s)*64 + lane];
  out[g*64 + lane] = sum / fmaxf((float)gcnt[g], 1.f);
}

extern "C" void kernel_launch(void* const* d_in, const int* in_sizes, int n_in,
                              void* d_out, int out_size, void* d_ws, size_t ws_size,
                              hipStream_t stream){
  const float* h    = (const float*)d_in[0];
  const int*   esrc = (const int*)d_in[1];
  const int*   edst = (const int*)d_in[2];
  const int*   gid  = (const int*)d_in[3];
  const float* ws0  = (const float*)d_in[4];
  const float* wn0  = (const float*)d_in[5];
  const float* bs0  = (const float*)d_in[6];
  const float* ws1  = (const float*)d_in[7];
  const float* wn1  = (const float*)d_in[8];
  const float* bs1  = (const float*)d_in[9];
  const float* ws2  = (const float*)d_in[10];
  const float* wn2  = (const float*)d_in[11];
  const float* bs2  = (const float*)d_in[12];
  const float* lw0  = (const float*)d_in[13];
  const float* lb0  = (const float*)d_in[14];
  const float* lw1  = (const float*)d_in[15];
  const float* lb1  = (const float*)d_in[16];
  const float* lw2  = (const float*)d_in[17];
  const float* lb2  = (const float*)d_in[18];
  float* out = (float*)d_out;

  char* p = (char*)d_ws;
  auto alloc = [&](size_t b)->char*{ char* r = p; p += (b + 255) & ~(size_t)255; return r; };
  char* X0 = alloc((size_t)M_NODES*256);
  char* XA = alloc((size_t)M_NODES*256);
  char* XB = alloc((size_t)M_NODES*256);
  char* G  = alloc((size_t)M_NODES*256);
  float* xF = (float*)alloc((size_t)M_NODES*64*4);
  float* pp = (float*)alloc((size_t)64*8*64*4);
  char* zbase = p;                       // contiguous zero-init region
  int* gcnt  = (int*)alloc(256);
  size_t zbytes = (size_t)(p - zbase);
  unsigned* part = (unsigned*)alloc((size_t)B_H*HWORDS*4);
  int* cbase = (int*)alloc((size_t)B_H*M_NODES*4);
  int* rp    = (int*)alloc((size_t)(M_NODES+1)*4);
  int* col   = (int*)alloc((size_t)E_EDGES*4);
  int* bsum  = (int*)alloc((size_t)SCAN_B*4);
  int* boff  = (int*)alloc((size_t)SCAN_B*4);
  unsigned short* W0h = (unsigned short*)alloc(128*256*2);
  unsigned short* W0l = (unsigned short*)alloc(128*256*2);
  unsigned short* W1h = (unsigned short*)alloc(128*256*2);
  unsigned short* W1l = (unsigned short*)alloc(128*256*2);
  unsigned short* W2h = (unsigned short*)alloc(128*256*2);
  unsigned short* W2l = (unsigned short*)alloc(128*256*2);
  unsigned short* L0h = (unsigned short*)alloc(128*128*2);
  unsigned short* L0l = (unsigned short*)alloc(128*128*2);
  unsigned short* L1h = (unsigned short*)alloc(128*128*2);
  unsigned short* L1l = (unsigned short*)alloc(128*128*2);
  unsigned short* L2h = (unsigned short*)alloc(64*128*2);
  unsigned short* L2l = (unsigned short*)alloc(64*128*2);

  hipMemsetAsync(zbase, 0, zbytes, stream);
  k_prep<<<544 + (M_NODES*16 + 255)/256, 256, 0, stream>>>(
      ws0, wn0, ws1, wn1, ws2, wn2, lw0, lw1, lw2, h,
      W0h, W0l, W1h, W1l, W2h, W2l, L0h, L0l, L1h, L1l, L2h, L2l, X0);
  k_hist<<<B_H, 256, HWORDS*4, stream>>>(edst, part);
  k_scan1<<<SCAN_B, 256, 0, stream>>>(part, rp, bsum);
  k_scan2<<<1, 256, 0, stream>>>(bsum, boff);
  k_cbase<<<SCAN_B, 256, 0, stream>>>(rp, boff, part, cbase, gid, gcnt);
  k_fill<<<B_H, 256, HWORDS*4, stream>>>(esrc, edst, cbase, col);

  const int gGrid = (M_NODES + 127)/128;
  const int aGrid = (M_NODES + 15)/16;
  // SAGE layer 0 (relu)
  k_agg<<<aGrid, 256, 0, stream>>>(X0, rp, col, G);
  k_gemm<256,8,true ,true ><<<gGrid,256,0,stream>>>(X0, G, W0h, W0l, bs0, XA);
  // SAGE layer 1 (relu)
  k_agg<<<aGrid, 256, 0, stream>>>(XA, rp, col, G);
  k_gemm<256,8,true ,true ><<<gGrid,256,0,stream>>>(XA, G, W1h, W1l, bs1, XB);
  // SAGE layer 2 (no relu)
  k_agg<<<aGrid, 256, 0, stream>>>(XB, rp, col, G);
  k_gemm<256,8,false,true ><<<gGrid,256,0,stream>>>(XB, G, W2h, W2l, bs2, XA);
  // MLP
  k_gemm<128,8,true ,true ><<<gGrid,256,0,stream>>>(XA, nullptr, L0h, L0l, lb0, XB);
  k_gemm<128,8,true ,true ><<<gGrid,256,0,stream>>>(XB, nullptr, L1h, L1l, lb1, XA);
  k_gemm<128,4,false,false><<<gGrid,256,0,stream>>>(XA, nullptr, L2h, L2l, lb2, (char*)xF);
  // pooling
  k_pool1<<<512, 256, 0, stream>>>(xF, gcnt, pp);
  k_pool2<<<64, 64, 0, stream>>>(pp, gcnt, out);
}

// Round 9
// 216.454 us; speedup vs baseline: 1.4106x; 1.0349x over previous
//
#include <hip/hip_runtime.h>

#define M_NODES 50000
#define E_EDGES 600000
#define SCAN_B ((M_NODES + 255) / 256)
#define B_H 64
#define EPB (E_EDGES / B_H)          // 9375
#define HWORDS (M_NODES / 2)         // 25000 packed u32 = 100 KB LDS

typedef short bf16x8 __attribute__((ext_vector_type(8)));
typedef float f32x4 __attribute__((ext_vector_type(4)));

__device__ __forceinline__ unsigned short f2bf(float f){
  unsigned u = __float_as_uint(f);
  u += 0x7FFFu + ((u >> 16) & 1u);
  return (unsigned short)(u >> 16);
}
__device__ __forceinline__ float bf2f(unsigned short h){
  return __uint_as_float(((unsigned)h) << 16);
}
__device__ __forceinline__ void gl_lds16(const void* g, void* l){
  __builtin_amdgcn_global_load_lds(
      (const __attribute__((address_space(1))) unsigned int*)g,
      (__attribute__((address_space(3))) unsigned int*)l, 16, 0, 0);
}

// ---------- fused: weight prep (split hi/lo, transposed) + activation cast (pure bf16) ----------
__global__ __launch_bounds__(256) void k_prep(
    const float* __restrict__ ws0, const float* __restrict__ wn0,
    const float* __restrict__ ws1, const float* __restrict__ wn1,
    const float* __restrict__ ws2, const float* __restrict__ wn2,
    const float* __restrict__ lw0, const float* __restrict__ lw1,
    const float* __restrict__ lw2, const float* __restrict__ H,
    unsigned short* __restrict__ W0h, unsigned short* __restrict__ W0l,
    unsigned short* __restrict__ W1h, unsigned short* __restrict__ W1l,
    unsigned short* __restrict__ W2h, unsigned short* __restrict__ W2l,
    unsigned short* __restrict__ L0h, unsigned short* __restrict__ L0l,
    unsigned short* __restrict__ L1h, unsigned short* __restrict__ L1l,
    unsigned short* __restrict__ L2h, unsigned short* __restrict__ L2l,
    char* __restrict__ X){
  const int b = blockIdx.x, t = threadIdx.x;
  if (b < 384){                      // stacked [ws;wn] -> [N=128][K=256]
    const int wsel = b >> 7;
    const int i = (b & 127)*256 + t;
    const float* Wa = wsel==0?ws0:(wsel==1?ws1:ws2);
    const float* Wb = wsel==0?wn0:(wsel==1?wn1:wn2);
    unsigned short* Th = wsel==0?W0h:(wsel==1?W1h:W2h);
    unsigned short* Tl = wsel==0?W0l:(wsel==1?W1l:W2l);
    int n = i >> 8, k = i & 255;
    float v = (k < 128) ? Wa[k*128 + n] : Wb[(k-128)*128 + n];
    unsigned short hi = f2bf(v);
    Th[n*256 + k] = hi; Tl[n*256 + k] = f2bf(v - bf2f(hi));
  } else if (b < 512){               // lw0/lw1 [128][128] -> [128][128]^T
    const int lsel = (b - 384) >> 6;
    const int i = ((b - 384) & 63)*256 + t;
    const float* W = lsel==0?lw0:lw1;
    unsigned short* Th = lsel==0?L0h:L1h;
    unsigned short* Tl = lsel==0?L0l:L1l;
    int n = i >> 7, k = i & 127;
    float v = W[k*128 + n];
    unsigned short hi = f2bf(v);
    Th[n*128 + k] = hi; Tl[n*128 + k] = f2bf(v - bf2f(hi));
  } else if (b < 544){               // lw2 [128][64] -> [64][128]^T
    const int i = (b - 512)*256 + t;
    if (i >= 64*128) return;
    int n = i >> 7, k = i & 127;
    float v = lw2[k*64 + n];
    unsigned short hi = f2bf(v);
    L2h[n*128 + k] = hi; L2l[n*128 + k] = f2bf(v - bf2f(hi));
  } else {                           // cast h -> pure-bf16 rows (256B)
    const int i = (b - 544)*256 + t; // over M*16 granules of 16B
    if (i >= M_NODES*16) return;
    const int n = i >> 4, j = i & 15;
    const float4 f0 = *reinterpret_cast<const float4*>(H + (size_t)n*128 + j*8);
    const float4 f1 = *reinterpret_cast<const float4*>(H + (size_t)n*128 + j*8 + 4);
    uint4 hq;
    hq.x = (unsigned)f2bf(f0.x) | ((unsigned)f2bf(f0.y) << 16);
    hq.y = (unsigned)f2bf(f0.z) | ((unsigned)f2bf(f0.w) << 16);
    hq.z = (unsigned)f2bf(f1.x) | ((unsigned)f2bf(f1.y) << 16);
    hq.w = (unsigned)f2bf(f1.z) | ((unsigned)f2bf(f1.w) << 16);
    *reinterpret_cast<uint4*>(X + (size_t)n*256 + j*16) = hq;
  }
}

// ---------- degree histogram: LDS-privatized, packed 2xu16, no global atomics ----------
__global__ __launch_bounds__(256) void k_hist(const int* __restrict__ dst,
    unsigned* __restrict__ part){
  extern __shared__ unsigned lds[];
  const int b = blockIdx.x, tid = threadIdx.x;
  uint4* lds4 = reinterpret_cast<uint4*>(lds);
  for (int j = tid; j < HWORDS/4; j += 256) lds4[j] = make_uint4(0u,0u,0u,0u);
  __syncthreads();
  const int beg = b*EPB, end = beg + EPB;
  for (int e = beg + tid; e < end; e += 256){
    const int d = dst[e];
    atomicAdd(&lds[d >> 1], 1u << ((d & 1)*16));
  }
  __syncthreads();
  unsigned* prow = part + (size_t)b*HWORDS;
  for (int j = tid; j < HWORDS; j += 256) prow[j] = lds[j];
}

// ---------- scan phase 1: block-local prefix over summed partials ----------
__global__ __launch_bounds__(256) void k_scan1(const unsigned* __restrict__ part,
    int* __restrict__ rp, int* __restrict__ bsum){
  __shared__ int wsum[4];
  int b = blockIdx.x, tid = threadIdx.x, lane = tid & 63, w = tid >> 6;
  int i = b*256 + tid;
  int v = 0;
  if (i < M_NODES){
    const int word = i >> 1, sh = (i & 1)*16;
    for (int c = 0; c < B_H; c++)
      v += (part[(size_t)c*HWORDS + word] >> sh) & 0xffffu;
  }
  int x = v;
  #pragma unroll
  for (int off = 1; off < 64; off <<= 1){
    int y = __shfl_up(x, off);
    if (lane >= off) x += y;
  }
  if (lane == 63) wsum[w] = x;
  __syncthreads();
  int pre = 0;
  #pragma unroll
  for (int j = 0; j < 4; j++) if (j < w) pre += wsum[j];
  if (i < M_NODES) rp[i+1] = pre + x;
  if (tid == 255) bsum[b] = pre + x;
}

// ---------- finalize rp + per-block segment bases + gid histogram (scan2 folded in) ----------
__global__ __launch_bounds__(256) void k_cbase(int* __restrict__ rp,
    const int* __restrict__ bsum, const unsigned* __restrict__ part,
    int* __restrict__ cbase, const int* __restrict__ gid, int* __restrict__ gcnt){
  __shared__ int s_bo;
  const int b = blockIdx.x, tid = threadIdx.x;
  const int i = b*256 + tid;
  const bool valid = i < M_NODES;
  const int lane = tid & 63, wave = tid >> 6;
  // read local prefixes before overwriting
  const int lp = (tid == 0) ? 0 : (valid ? rp[i] : 0);          // local exclusive at i
  const int li = valid ? rp[i+1] : 0;                           // local inclusive
  // block offset = sum of bsum[0..b-1] (computed by wave 0)
  if (wave == 0){
    int s = 0;
    for (int j = lane; j < b; j += 64) s += bsum[j];
    #pragma unroll
    for (int off = 32; off > 0; off >>= 1) s += __shfl_xor(s, off);
    if (lane == 0) s_bo = s;
  }
  __syncthreads();
  const int bo = s_bo;
  if (valid) rp[i+1] = li + bo;
  if (i == 0) rp[0] = 0;
  // gid run-length histogram (gid is sorted)
  {
    int g = valid ? gid[i] : -1;
    int gp = __shfl_up(g, 1);
    bool bnd = valid && (lane == 0 || g != gp);
    unsigned long long mbnd = __ballot(bnd);
    unsigned long long mval = __ballot(valid);
    if (bnd){
      unsigned long long above = (lane == 63) ? 0ull : (mbnd >> (lane+1));
      int nxt = above ? (lane + 1 + (__ffsll((long long)above) - 1)) : 64;
      int lastvalid = 63 - __clzll((long long)mval);
      int runend = min(nxt, lastvalid + 1);
      atomicAdd(&gcnt[g], runend - lane);
    }
  }
  if (!valid) return;
  const int word = i >> 1, sh = (i & 1)*16;
  int base = lp + bo;
  for (int c = 0; c < B_H; c++){
    cbase[(size_t)c*M_NODES + i] = base;
    base += (part[(size_t)c*HWORDS + word] >> sh) & 0xffffu;
  }
}

// ---------- CSR fill: LDS rank counters, no global atomics ----------
__global__ __launch_bounds__(256) void k_fill(const int* __restrict__ src,
    const int* __restrict__ dst, const int* __restrict__ cbase,
    int* __restrict__ col){
  extern __shared__ unsigned lds[];
  const int b = blockIdx.x, tid = threadIdx.x;
  uint4* lds4 = reinterpret_cast<uint4*>(lds);
  for (int j = tid; j < HWORDS/4; j += 256) lds4[j] = make_uint4(0u,0u,0u,0u);
  __syncthreads();
  const int beg = b*EPB, end = beg + EPB;
  const int* cb = cbase + (size_t)b*M_NODES;
  for (int e = beg + tid; e < end; e += 256){
    const int d = dst[e];
    const int sh = (d & 1)*16;
    const unsigned old = atomicAdd(&lds[d >> 1], 1u << sh);
    const int rank = (old >> sh) & 0xffffu;
    col[cb[d] + rank] = src[e];
  }
}

// ---------- mean aggregation over pure-bf16 rows (256B), quarter-wave per node ----------
#define ACC8(u) \
  a[0] += __uint_as_float((u).x << 16); a[1] += __uint_as_float((u).x & 0xFFFF0000u); \
  a[2] += __uint_as_float((u).y << 16); a[3] += __uint_as_float((u).y & 0xFFFF0000u); \
  a[4] += __uint_as_float((u).z << 16); a[5] += __uint_as_float((u).z & 0xFFFF0000u); \
  a[6] += __uint_as_float((u).w << 16); a[7] += __uint_as_float((u).w & 0xFFFF0000u);

__global__ __launch_bounds__(256) void k_agg(const char* __restrict__ X,
    const int* __restrict__ rp, const int* __restrict__ col, char* __restrict__ G){
  const int q  = threadIdx.x >> 4;          // 16 quarters per block
  const int ql = threadIdx.x & 15;
  const int v = blockIdx.x*16 + q;
  if (v >= M_NODES) return;
  const int beg = rp[v], end = rp[v+1];
  const int off = ql*16;
  float a[8];
  #pragma unroll
  for (int k = 0; k < 8; k++) a[k] = 0.f;
  int e = beg;
  for (; e + 4 <= end; e += 4){
    const int s0 = col[e], s1 = col[e+1], s2 = col[e+2], s3 = col[e+3];
    const uint4 x0 = *reinterpret_cast<const uint4*>(X + (size_t)s0*256 + off);
    const uint4 x1 = *reinterpret_cast<const uint4*>(X + (size_t)s1*256 + off);
    const uint4 x2 = *reinterpret_cast<const uint4*>(X + (size_t)s2*256 + off);
    const uint4 x3 = *reinterpret_cast<const uint4*>(X + (size_t)s3*256 + off);
    ACC8(x0); ACC8(x1); ACC8(x2); ACC8(x3);
  }
  for (; e < end; e++){
    const uint4 x0 = *reinterpret_cast<const uint4*>(X + (size_t)col[e]*256 + off);
    ACC8(x0);
  }
  const float inv = 1.f / fmaxf((float)(end - beg), 1.f);
  uint4 hq;
  unsigned hw[4];
  #pragma unroll
  for (int k = 0; k < 4; k++){
    const float x0 = a[2*k]*inv, x1 = a[2*k+1]*inv;
    hw[k] = (unsigned)f2bf(x0) | ((unsigned)f2bf(x1) << 16);
  }
  hq.x = hw[0]; hq.y = hw[1]; hq.z = hw[2]; hq.w = hw[3];
  *reinterpret_cast<uint4*>(G + (size_t)v*256 + off) = hq;
}

// ---------- SAGE GEMM: pure-bf16 A (global_load_lds), split W (hi+lo), 2 MFMAs/tile ----------
template<int KL, int NT, bool RELU>
__global__ __launch_bounds__(256) void k_gemm(
    const char* __restrict__ A1, const char* __restrict__ A2,
    const unsigned short* __restrict__ Wh, const unsigned short* __restrict__ Wl,
    const float* __restrict__ bias, char* __restrict__ Y){
  constexpr int NOUT = NT * 16;
  constexpr int KC = KL / 64;
  constexpr int NBI = NOUT / 32;
  __shared__ __align__(16) char sA [128*128];
  __shared__ __align__(16) char sBh[NOUT*128];
  __shared__ __align__(16) char sBl[NOUT*128];
  const int tid = threadIdx.x;
  const int wave = tid >> 6, lane = tid & 63;
  const int blockRow = blockIdx.x * 128;
  const int srow = lane >> 3, slot = lane & 7;
  const int sb = (slot*16) ^ (srow << 4);
  size_t aoff[4];
  #pragma unroll
  for (int i = 0; i < 4; i++){
    int grow = blockRow + wave*32 + i*8 + srow;
    if (grow >= M_NODES) grow = M_NODES - 1;
    aoff[i] = (size_t)grow*256 + sb;
  }
  size_t boff[NBI];
  #pragma unroll
  for (int i = 0; i < NBI; i++){
    int n = wave*(NOUT/4) + i*8 + srow;
    boff[i] = (size_t)n*(2*KL) + sb;
  }
  f32x4 acc[2][NT];
  #pragma unroll
  for (int a = 0; a < 2; a++)
    #pragma unroll
    for (int i = 0; i < NT; i++)
      #pragma unroll
      for (int r = 0; r < 4; r++) acc[a][i][r] = 0.f;

  for (int kc = 0; kc < KC; kc++){
    const char* Ap; int acolb;
    if (KL == 256 && kc >= 2){ Ap = A2; acolb = (kc - 2)*128; }
    else                     { Ap = A1; acolb = kc*128; }
    const int bcolb = kc*128;
    __syncthreads();
    #pragma unroll
    for (int i = 0; i < 4; i++){
      const int lr = (wave*32 + i*8)*128;
      gl_lds16(Ap + aoff[i] + acolb, sA + lr);
    }
    #pragma unroll
    for (int i = 0; i < NBI; i++){
      const int lr = (wave*(NOUT/4) + i*8)*128;
      gl_lds16(reinterpret_cast<const char*>(Wh) + boff[i] + bcolb, sBh + lr);
      gl_lds16(reinterpret_cast<const char*>(Wl) + boff[i] + bcolb, sBl + lr);
    }
    __syncthreads();
    #pragma unroll
    for (int ks = 0; ks < 2; ks++){
      const int kb = (ks*32 + ((lane >> 4) * 8)) * 2;
      bf16x8 ah[2];
      #pragma unroll
      for (int ar = 0; ar < 2; ar++){
        const int arow = wave*32 + ar*16 + (lane & 15);
        ah[ar] = *reinterpret_cast<const bf16x8*>(sA + arow*128 + (kb ^ ((arow & 7) << 4)));
      }
      #pragma unroll
      for (int nt = 0; nt < NT; nt++){
        const int n = nt*16 + (lane & 15);
        const int bb = n*128 + (kb ^ ((n & 7) << 4));
        const bf16x8 bh = *reinterpret_cast<const bf16x8*>(sBh + bb);
        const bf16x8 bl = *reinterpret_cast<const bf16x8*>(sBl + bb);
        #pragma unroll
        for (int ar = 0; ar < 2; ar++){
          acc[ar][nt] = __builtin_amdgcn_mfma_f32_16x16x32_bf16(ah[ar], bh, acc[ar][nt], 0, 0, 0);
          acc[ar][nt] = __builtin_amdgcn_mfma_f32_16x16x32_bf16(ah[ar], bl, acc[ar][nt], 0, 0, 0);
        }
      }
    }
  }
  const int r0 = (lane >> 4) * 4;
  #pragma unroll
  for (int ar = 0; ar < 2; ar++){
    const int growb = blockRow + wave*32 + ar*16 + r0;
    #pragma unroll
    for (int nt = 0; nt < NT; nt++){
      const int colx = nt*16 + (lane & 15);
      const float bsv = bias[colx];
      #pragma unroll
      for (int r = 0; r < 4; r++){
        const int grow = growb + r;
        float vv = acc[ar][nt][r] + bsv;
        if (RELU) vv = fmaxf(vv, 0.f);
        const float vo = __shfl_xor(vv, 1);
        if ((lane & 1) == 0 && grow < M_NODES){
          const unsigned hv = (unsigned)f2bf(vv) | ((unsigned)f2bf(vo) << 16);
          *reinterpret_cast<unsigned*>(Y + (size_t)grow*256 + colx*2) = hv;
        }
      }
    }
  }
}

// ---------- fused MLP: 3 layers in one kernel, intermediates in LDS ----------
__global__ __launch_bounds__(256) void k_mlp(const char* __restrict__ X,
    const unsigned short* __restrict__ L0h, const unsigned short* __restrict__ L0l,
    const unsigned short* __restrict__ L1h, const unsigned short* __restrict__ L1l,
    const unsigned short* __restrict__ L2h, const unsigned short* __restrict__ L2l,
    const float* __restrict__ b0, const float* __restrict__ b1,
    const float* __restrict__ b2, float* __restrict__ Y){
  __shared__ __align__(16) char sA [128*128];      // 16KB per-kc staging
  __shared__ __align__(16) char sBh[128*128];
  __shared__ __align__(16) char sBl[128*128];
  __shared__ __align__(16) char sX [2][128*128];   // 32KB full intermediate rows (2 planes)
  const int tid = threadIdx.x;
  const int wave = tid >> 6, lane = tid & 63;
  const int blockRow = blockIdx.x * 128;
  const int srow = lane >> 3, slot = lane & 7;
  const int sb = (slot*16) ^ (srow << 4);
  size_t aoff[4];
  #pragma unroll
  for (int i = 0; i < 4; i++){
    int grow = blockRow + wave*32 + i*8 + srow;
    if (grow >= M_NODES) grow = M_NODES - 1;
    aoff[i] = (size_t)grow*256 + sb;
  }
  const int r0 = (lane >> 4) * 4;
  f32x4 acc[2][8];

  // ===== layer 1: sA(global X) x L0 -> sX =====
  #pragma unroll
  for (int a = 0; a < 2; a++)
    #pragma unroll
    for (int i = 0; i < 8; i++)
      #pragma unroll
      for (int r = 0; r < 4; r++) acc[a][i][r] = 0.f;
  for (int kc = 0; kc < 2; kc++){
    __syncthreads();
    #pragma unroll
    for (int i = 0; i < 4; i++){
      const int lr = (wave*32 + i*8)*128;
      gl_lds16(X + aoff[i] + kc*128, sA + lr);
      const size_t wo = (size_t)(wave*32 + i*8 + srow)*256 + kc*128 + sb;
      gl_lds16(reinterpret_cast<const char*>(L0h) + wo, sBh + lr);
      gl_lds16(reinterpret_cast<const char*>(L0l) + wo, sBl + lr);
    }
    __syncthreads();
    #pragma unroll
    for (int ks = 0; ks < 2; ks++){
      const int kb = (ks*32 + ((lane >> 4) * 8)) * 2;
      bf16x8 ah[2];
      #pragma unroll
      for (int ar = 0; ar < 2; ar++){
        const int arow = wave*32 + ar*16 + (lane & 15);
        ah[ar] = *reinterpret_cast<const bf16x8*>(sA + arow*128 + (kb ^ ((arow & 7) << 4)));
      }
      #pragma unroll
      for (int nt = 0; nt < 8; nt++){
        const int n = nt*16 + (lane & 15);
        const int bb = n*128 + (kb ^ ((n & 7) << 4));
        const bf16x8 bh = *reinterpret_cast<const bf16x8*>(sBh + bb);
        const bf16x8 bl = *reinterpret_cast<const bf16x8*>(sBl + bb);
        #pragma unroll
        for (int ar = 0; ar < 2; ar++){
          acc[ar][nt] = __builtin_amdgcn_mfma_f32_16x16x32_bf16(ah[ar], bh, acc[ar][nt], 0, 0, 0);
          acc[ar][nt] = __builtin_amdgcn_mfma_f32_16x16x32_bf16(ah[ar], bl, acc[ar][nt], 0, 0, 0);
        }
      }
    }
  }
  #pragma unroll
  for (int ar = 0; ar < 2; ar++){
    const int lrow0 = wave*32 + ar*16 + r0;
    #pragma unroll
    for (int nt = 0; nt < 8; nt++){
      const int colx = nt*16 + (lane & 15);
      const float bsv = b0[colx];
      #pragma unroll
      for (int r = 0; r < 4; r++){
        const int lrow = lrow0 + r;
        float vv = fmaxf(acc[ar][nt][r] + bsv, 0.f);
        const float vo = __shfl_xor(vv, 1);
        if ((lane & 1) == 0){
          const unsigned hv = (unsigned)f2bf(vv) | ((unsigned)f2bf(vo) << 16);
          const int k2 = (colx & 63)*2;
          *reinterpret_cast<unsigned*>(sX[colx >> 6] + lrow*128 + (k2 ^ ((lrow & 7) << 4))) = hv;
        }
      }
    }
  }
  // ===== layer 2: sX x L1 -> sX =====
  #pragma unroll
  for (int a = 0; a < 2; a++)
    #pragma unroll
    for (int i = 0; i < 8; i++)
      #pragma unroll
      for (int r = 0; r < 4; r++) acc[a][i][r] = 0.f;
  for (int kc = 0; kc < 2; kc++){
    __syncthreads();  // also orders epilogue-1 sX writes before reads
    #pragma unroll
    for (int i = 0; i < 4; i++){
      const int lr = (wave*32 + i*8)*128;
      const size_t wo = (size_t)(wave*32 + i*8 + srow)*256 + kc*128 + sb;
      gl_lds16(reinterpret_cast<const char*>(L1h) + wo, sBh + lr);
      gl_lds16(reinterpret_cast<const char*>(L1l) + wo, sBl + lr);
    }
    __syncthreads();
    #pragma unroll
    for (int ks = 0; ks < 2; ks++){
      const int kb = (ks*32 + ((lane >> 4) * 8)) * 2;
      bf16x8 ah[2];
      #pragma unroll
      for (int ar = 0; ar < 2; ar++){
        const int arow = wave*32 + ar*16 + (lane & 15);
        ah[ar] = *reinterpret_cast<const bf16x8*>(sX[kc] + arow*128 + (kb ^ ((arow & 7) << 4)));
      }
      #pragma unroll
      for (int nt = 0; nt < 8; nt++){
        const int n = nt*16 + (lane & 15);
        const int bb = n*128 + (kb ^ ((n & 7) << 4));
        const bf16x8 bh = *reinterpret_cast<const bf16x8*>(sBh + bb);
        const bf16x8 bl = *reinterpret_cast<const bf16x8*>(sBl + bb);
        #pragma unroll
        for (int ar = 0; ar < 2; ar++){
          acc[ar][nt] = __builtin_amdgcn_mfma_f32_16x16x32_bf16(ah[ar], bh, acc[ar][nt], 0, 0, 0);
          acc[ar][nt] = __builtin_amdgcn_mfma_f32_16x16x32_bf16(ah[ar], bl, acc[ar][nt], 0, 0, 0);
        }
      }
    }
  }
  __syncthreads();  // all waves done reading sX before overwrite
  #pragma unroll
  for (int ar = 0; ar < 2; ar++){
    const int lrow0 = wave*32 + ar*16 + r0;
    #pragma unroll
    for (int nt = 0; nt < 8; nt++){
      const int colx = nt*16 + (lane & 15);
      const float bsv = b1[colx];
      #pragma unroll
      for (int r = 0; r < 4; r++){
        const int lrow = lrow0 + r;
        float vv = fmaxf(acc[ar][nt][r] + bsv, 0.f);
        const float vo = __shfl_xor(vv, 1);
        if ((lane & 1) == 0){
          const unsigned hv = (unsigned)f2bf(vv) | ((unsigned)f2bf(vo) << 16);
          const int k2 = (colx & 63)*2;
          *reinterpret_cast<unsigned*>(sX[colx >> 6] + lrow*128 + (k2 ^ ((lrow & 7) << 4))) = hv;
        }
      }
    }
  }
  // ===== layer 3: sX x L2 -> global fp32 (NOUT=64) =====
  #pragma unroll
  for (int a = 0; a < 2; a++)
    #pragma unroll
    for (int i = 0; i < 4; i++)
      #pragma unroll
      for (int r = 0; r < 4; r++) acc[a][i][r] = 0.f;
  for (int kc = 0; kc < 2; kc++){
    __syncthreads();
    #pragma unroll
    for (int i = 0; i < 2; i++){
      const int lr = (wave*16 + i*8)*128;
      const size_t wo = (size_t)(wave*16 + i*8 + srow)*256 + kc*128 + sb;
      gl_lds16(reinterpret_cast<const char*>(L2h) + wo, sBh + lr);
      gl_lds16(reinterpret_cast<const char*>(L2l) + wo, sBl + lr);
    }
    __syncthreads();
    #pragma unroll
    for (int ks = 0; ks < 2; ks++){
      const int kb = (ks*32 + ((lane >> 4) * 8)) * 2;
      bf16x8 ah[2];
      #pragma unroll
      for (int ar = 0; ar < 2; ar++){
        const int arow = wave*32 + ar*16 + (lane & 15);
        ah[ar] = *reinterpret_cast<const bf16x8*>(sX[kc] + arow*128 + (kb ^ ((arow & 7) << 4)));
      }
      #pragma unroll
      for (int nt = 0; nt < 4; nt++){
        const int n = nt*16 + (lane & 15);
        const int bb = n*128 + (kb ^ ((n & 7) << 4));
        const bf16x8 bh = *reinterpret_cast<const bf16x8*>(sBh + bb);
        const bf16x8 bl = *reinterpret_cast<const bf16x8*>(sBl + bb);
        #pragma unroll
        for (int ar = 0; ar < 2; ar++){
          acc[ar][nt] = __builtin_amdgcn_mfma_f32_16x16x32_bf16(ah[ar], bh, acc[ar][nt], 0, 0, 0);
          acc[ar][nt] = __builtin_amdgcn_mfma_f32_16x16x32_bf16(ah[ar], bl, acc[ar][nt], 0, 0, 0);
        }
      }
    }
  }
  #pragma unroll
  for (int ar = 0; ar < 2; ar++){
    const int growb = blockRow + wave*32 + ar*16 + r0;
    #pragma unroll
    for (int nt = 0; nt < 4; nt++){
      const int colx = nt*16 + (lane & 15);
      const float bsv = b2[colx];
      #pragma unroll
      for (int r = 0; r < 4; r++){
        const int grow = growb + r;
        if (grow < M_NODES)
          Y[(size_t)grow*64 + colx] = acc[ar][nt][r] + bsv;
      }
    }
  }
}

// ---------- pooling stage 1: 8 sub-chunks per graph ----------
__global__ __launch_bounds__(256) void k_pool1(const float* __restrict__ Xf,
    const int* __restrict__ gcnt, float* __restrict__ pp){
  const int g = blockIdx.x >> 3, s = blockIdx.x & 7;
  const int tid = threadIdx.x, w = tid >> 6, lane = tid & 63;
  __shared__ int sstart;
  __shared__ float part[4][64];
  if (w == 0){
    int v = gcnt[lane];
    int x = v;
    #pragma unroll
    for (int off = 1; off < 64; off <<= 1){
      int y = __shfl_up(x, off);
      if (lane >= off) x += y;
    }
    if (lane == g) sstart = x - v;
  }
  __syncthreads();
  const int cg = gcnt[g];
  const int Lc = (cg + 7) >> 3;
  const int nbeg = sstart + s*Lc;
  const int nend = min(nbeg + Lc, sstart + cg);
  float a0 = 0.f, a1 = 0.f;
  int i = nbeg + w;
  for (; i + 4 < nend; i += 8){
    a0 += Xf[(size_t)i*64 + lane];
    a1 += Xf[(size_t)(i+4)*64 + lane];
  }
  if (i < nend) a0 += Xf[(size_t)i*64 + lane];
  part[w][lane] = a0 + a1;
  __syncthreads();
  if (w == 0)
    pp[(size_t)(g*8 + s)*64 + lane] = part[0][lane] + part[1][lane] + part[2][lane] + part[3][lane];
}

// ---------- pooling stage 2 ----------
__global__ __launch_bounds__(64) void k_pool2(const float* __restrict__ pp,
    const int* __restrict__ gcnt, float* __restrict__ out){
  const int g = blockIdx.x, lane = threadIdx.x;
  float sum = 0.f;
  #pragma unroll
  for (int s = 0; s < 8; s++) sum += pp[(size_t)(g*8 + s)*64 + lane];
  out[g*64 + lane] = sum / fmaxf((float)gcnt[g], 1.f);
}

extern "C" void kernel_launch(void* const* d_in, const int* in_sizes, int n_in,
                              void* d_out, int out_size, void* d_ws, size_t ws_size,
                              hipStream_t stream){
  const float* h    = (const float*)d_in[0];
  const int*   esrc = (const int*)d_in[1];
  const int*   edst = (const int*)d_in[2];
  const int*   gid  = (const int*)d_in[3];
  const float* ws0  = (const float*)d_in[4];
  const float* wn0  = (const float*)d_in[5];
  const float* bs0  = (const float*)d_in[6];
  const float* ws1  = (const float*)d_in[7];
  const float* wn1  = (const float*)d_in[8];
  const float* bs1  = (const float*)d_in[9];
  const float* ws2  = (const float*)d_in[10];
  const float* wn2  = (const float*)d_in[11];
  const float* bs2  = (const float*)d_in[12];
  const float* lw0  = (const float*)d_in[13];
  const float* lb0  = (const float*)d_in[14];
  const float* lw1  = (const float*)d_in[15];
  const float* lb1  = (const float*)d_in[16];
  const float* lw2  = (const float*)d_in[17];
  const float* lb2  = (const float*)d_in[18];
  float* out = (float*)d_out;

  char* p = (char*)d_ws;
  auto alloc = [&](size_t b)->char*{ char* r = p; p += (b + 255) & ~(size_t)255; return r; };
  char* X0 = alloc((size_t)M_NODES*256);
  char* XA = alloc((size_t)M_NODES*256);
  char* XB = alloc((size_t)M_NODES*256);
  char* G  = alloc((size_t)M_NODES*256);
  float* xF = (float*)alloc((size_t)M_NODES*64*4);
  float* pp = (float*)alloc((size_t)64*8*64*4);
  char* zbase = p;                       // contiguous zero-init region
  int* gcnt  = (int*)alloc(256);
  size_t zbytes = (size_t)(p - zbase);
  unsigned* part = (unsigned*)alloc((size_t)B_H*HWORDS*4);
  int* cbase = (int*)alloc((size_t)B_H*M_NODES*4);
  int* rp    = (int*)alloc((size_t)(M_NODES+1)*4);
  int* col   = (int*)alloc((size_t)E_EDGES*4);
  int* bsum  = (int*)alloc((size_t)SCAN_B*4);
  unsigned short* W0h = (unsigned short*)alloc(128*256*2);
  unsigned short* W0l = (unsigned short*)alloc(128*256*2);
  unsigned short* W1h = (unsigned short*)alloc(128*256*2);
  unsigned short* W1l = (unsigned short*)alloc(128*256*2);
  unsigned short* W2h = (unsigned short*)alloc(128*256*2);
  unsigned short* W2l = (unsigned short*)alloc(128*256*2);
  unsigned short* L0h = (unsigned short*)alloc(128*128*2);
  unsigned short* L0l = (unsigned short*)alloc(128*128*2);
  unsigned short* L1h = (unsigned short*)alloc(128*128*2);
  unsigned short* L1l = (unsigned short*)alloc(128*128*2);
  unsigned short* L2h = (unsigned short*)alloc(64*128*2);
  unsigned short* L2l = (unsigned short*)alloc(64*128*2);

  hipMemsetAsync(zbase, 0, zbytes, stream);
  k_prep<<<544 + (M_NODES*16 + 255)/256, 256, 0, stream>>>(
      ws0, wn0, ws1, wn1, ws2, wn2, lw0, lw1, lw2, h,
      W0h, W0l, W1h, W1l, W2h, W2l, L0h, L0l, L1h, L1l, L2h, L2l, X0);
  k_hist<<<B_H, 256, HWORDS*4, stream>>>(edst, part);
  k_scan1<<<SCAN_B, 256, 0, stream>>>(part, rp, bsum);
  k_cbase<<<SCAN_B, 256, 0, stream>>>(rp, bsum, part, cbase, gid, gcnt);
  k_fill<<<B_H, 256, HWORDS*4, stream>>>(esrc, edst, cbase, col);

  const int gGrid = (M_NODES + 127)/128;
  const int aGrid = (M_NODES + 15)/16;
  // SAGE layer 0 (relu)
  k_agg<<<aGrid, 256, 0, stream>>>(X0, rp, col, G);
  k_gemm<256,8,true ><<<gGrid,256,0,stream>>>(X0, G, W0h, W0l, bs0, XA);
  // SAGE layer 1 (relu)
  k_agg<<<aGrid, 256, 0, stream>>>(XA, rp, col, G);
  k_gemm<256,8,true ><<<gGrid,256,0,stream>>>(XA, G, W1h, W1l, bs1, XB);
  // SAGE layer 2 (no relu)
  k_agg<<<aGrid, 256, 0, stream>>>(XB, rp, col, G);
  k_gemm<256,8,false><<<gGrid,256,0,stream>>>(XB, G, W2h, W2l, bs2, XA);
  // fused MLP (3 layers)
  k_mlp<<<gGrid, 256, 0, stream>>>(XA, L0h, L0l, L1h, L1l, L2h, L2l, lb0, lb1, lb2, xF);
  // pooling
  k_pool1<<<512, 256, 0, stream>>>(xF, gcnt, pp);
  k_pool2<<<64, 64, 0, stream>>>(pp, gcnt, out);
}